// Round 4
// baseline (1119.509 us; speedup 1.0000x reference)
//
#include <hip/hip_runtime.h>

#define Nn 100000
#define Ne 1600000
#define Fi 32
#define Hd 64
#define Ll 4
#define Gg 256
#define BN_EPS 1e-5f
#define NPB 128                      // nodes per bucket
#define NB  ((Nn + NPB - 1) / NPB)   // 782 buckets

// ---------------- setup kernels ----------------

__global__ void k_deg(const int* __restrict__ dst, int* __restrict__ deg) {
    int e = blockIdx.x * blockDim.x + threadIdx.x;
    if (e < Ne) atomicAdd(&deg[dst[e]], 1);
}

__global__ void k_dinv(const int* __restrict__ deg, float* __restrict__ dinv) {
    int n = blockIdx.x * blockDim.x + threadIdx.x;
    if (n < Nn) dinv[n] = rsqrtf((float)deg[n] + 1.0f);
}

// exclusive scan of deg into row_off (per-block), block sums to bsum
__global__ void k_scanA(const int* __restrict__ deg, int* __restrict__ row_off,
                        int* __restrict__ bsum) {
    __shared__ int s[256];
    int t = threadIdx.x;
    int i = blockIdx.x * 256 + t;
    int v = (i < Nn) ? deg[i] : 0;
    s[t] = v;
    __syncthreads();
    int x = v;
    for (int off = 1; off < 256; off <<= 1) {
        int u = (t >= off) ? s[t - off] : 0;
        __syncthreads();
        x += u;
        s[t] = x;
        __syncthreads();
    }
    if (i < Nn) row_off[i] = x - v;          // exclusive within block
    if (t == 255) bsum[blockIdx.x] = x;      // block total
}

__global__ void k_scanB(int* __restrict__ bsum, int nblk) {
    __shared__ int s[512];
    int t = threadIdx.x;
    int v = (t < nblk) ? bsum[t] : 0;
    s[t] = v;
    __syncthreads();
    int x = v;
    for (int off = 1; off < 512; off <<= 1) {
        int u = (t >= off) ? s[t - off] : 0;
        __syncthreads();
        x += u;
        s[t] = x;
        __syncthreads();
    }
    if (t < nblk) bsum[t] = x - v;           // exclusive block offsets
}

__global__ void k_scanC(int* __restrict__ row_off, const int* __restrict__ bsum) {
    int i = blockIdx.x * 256 + threadIdx.x;
    if (i < Nn) row_off[i] += bsum[blockIdx.x];
    if (i == 0) row_off[Nn] = Ne;
}

__global__ void k_binit(const int* __restrict__ row_off, int* __restrict__ bcursor) {
    int b = blockIdx.x * blockDim.x + threadIdx.x;
    if (b < NB) bcursor[b] = row_off[b * NPB];
}

// scatter edges into bucket-partitioned temp; packed src(17b) | ldst(7b)<<17
__global__ void k_bplace(const int* __restrict__ src, const int* __restrict__ dst,
                         int* __restrict__ bcursor, unsigned* __restrict__ tpack) {
    int e = blockIdx.x * blockDim.x + threadIdx.x;
    if (e >= Ne) return;
    int d = dst[e];
    int pos = atomicAdd(&bcursor[d >> 7], 1);
    tpack[pos] = (unsigned)src[e] | ((unsigned)(d & (NPB - 1)) << 17);
}

// per-bucket local CSR build: LDS histogram + scan + LDS cursors
__global__ __launch_bounds__(256) void k_csr(const int* __restrict__ row_off,
                                             const unsigned* __restrict__ tpack,
                                             int* __restrict__ esrc) {
    __shared__ int cnt[NPB], start[NPB];
    int b = blockIdx.x;
    int n0 = b * NPB;
    int n1 = min(n0 + NPB, Nn);
    int e0 = row_off[n0], e1 = row_off[n1];
    int t = threadIdx.x;
    if (t < NPB) cnt[t] = 0;
    __syncthreads();
    for (int e = e0 + t; e < e1; e += 256)
        atomicAdd(&cnt[tpack[e] >> 17], 1);
    __syncthreads();
    if (t < NPB) start[t] = cnt[t];
    __syncthreads();
    for (int off = 1; off < NPB; off <<= 1) {
        int x = (t < NPB && t >= off) ? start[t - off] : 0;
        __syncthreads();
        if (t < NPB) start[t] += x;
        __syncthreads();
    }
    if (t < NPB) cnt[t] = start[t] - cnt[t];   // exclusive start; reuse as cursor
    __syncthreads();
    for (int e = e0 + t; e < e1; e += 256) {
        unsigned v = tpack[e];
        int p = atomicAdd(&cnt[v >> 17], 1);
        esrc[e0 + p] = (int)(v & 0x1FFFFu);
    }
}

// per-graph node ranges via binary search over sorted batch
__global__ void k_gstart(const int* __restrict__ batch, int* __restrict__ gstart) {
    int g = threadIdx.x;   // 256 threads
    int lo = 0, hi = Nn;
    while (lo < hi) {
        int mid = (lo + hi) >> 1;
        if (batch[mid] < g) lo = mid + 1; else hi = mid;
    }
    gstart[g] = lo;
    if (g == 0) gstart[Gg] = Nn;
}

// ---------------- dense kernels ----------------

// fused: h[n] = x[n]@we + be (kept in regs), write h, hw[n] = h[n]@W0, write hw
__global__ __launch_bounds__(256) void k_embed_gemm(const float* __restrict__ x,
                                                    const float* __restrict__ we,
                                                    const float* __restrict__ be,
                                                    const float* __restrict__ W,
                                                    float* __restrict__ h,
                                                    float* __restrict__ hw) {
    int lane = threadIdx.x & 63;
    int wid  = blockIdx.x * (blockDim.x >> 6) + (threadIdx.x >> 6);
    int nw   = gridDim.x * (blockDim.x >> 6);
    float wE[Fi];
#pragma unroll
    for (int k = 0; k < Fi; k++) wE[k] = we[k * Hd + lane];
    float b = be[lane];
    float w0[Hd];
#pragma unroll
    for (int k = 0; k < Hd; k++) w0[k] = W[k * Hd + lane];
    for (int n = wid; n < Nn; n += nw) {
        float xv = (lane < Fi) ? x[n * Fi + lane] : 0.f;
        float hn = b;
#pragma unroll
        for (int k = 0; k < Fi; k++) hn = fmaf(__shfl(xv, k, 64), wE[k], hn);
        h[n * Hd + lane] = hn;
        float acc = 0.f;
#pragma unroll
        for (int k = 0; k < Hd; k++) acc = fmaf(__shfl(hn, k, 64), w0[k], acc);
        hw[n * Hd + lane] = acc;
    }
}

// fused: hn = relu(agg*sc+sh) + h  (bn-apply of prev layer), write h, hw = hn@W
__global__ __launch_bounds__(256) void k_gemmF(const float* __restrict__ agg,
                                               const float* __restrict__ bnsc,
                                               const float* __restrict__ bnsh,
                                               float* __restrict__ h,
                                               const float* __restrict__ W,
                                               float* __restrict__ hw) {
    int lane = threadIdx.x & 63;
    int wid  = blockIdx.x * (blockDim.x >> 6) + (threadIdx.x >> 6);
    int nw   = gridDim.x * (blockDim.x >> 6);
    float sc = bnsc[lane], shv = bnsh[lane];
    float w[Hd];
#pragma unroll
    for (int k = 0; k < Hd; k++) w[k] = W[k * Hd + lane];
    for (int n = wid; n < Nn; n += nw) {
        float a  = agg[(size_t)n * Hd + lane];
        float ho = h[(size_t)n * Hd + lane];
        float hn = fmaxf(fmaf(a, sc, shv), 0.f) + ho;
        h[(size_t)n * Hd + lane] = hn;
        float acc = 0.f;
#pragma unroll
        for (int k = 0; k < Hd; k++) acc = fmaf(__shfl(hn, k, 64), w[k], acc);
        hw[(size_t)n * Hd + lane] = acc;
    }
}

// gather + on-the-fly coef + fused bn-stats (sharded atomics)
__global__ __launch_bounds__(256) void k_gatherS(const float* __restrict__ hw,
                                                 const float* __restrict__ dinv,
                                                 const int* __restrict__ row_off,
                                                 const int* __restrict__ esrc,
                                                 const float* __restrict__ bias,
                                                 float* __restrict__ agg,
                                                 float* __restrict__ bnacc) {
    int g = threadIdx.x >> 4;   // node slot in block (16)
    int l = threadIdx.x & 15;   // lane in node group
    int node = blockIdx.x * 16 + g;   // Nn % 16 == 0, always valid
    float di = dinv[node];
    float scl = di * di;
    const float* hrow = hw + (size_t)node * Hd + l * 4;
    float4 acc;
    acc.x = hrow[0] * scl; acc.y = hrow[1] * scl; acc.z = hrow[2] * scl; acc.w = hrow[3] * scl;
    const float* bp = bias + l * 4;
    acc.x += bp[0]; acc.y += bp[1]; acc.z += bp[2]; acc.w += bp[3];

    int e = row_off[node], e1 = row_off[node + 1];
    for (; e + 1 < e1; e += 2) {
        int sa = esrc[e], sb = esrc[e + 1];
        float ca = dinv[sa] * di, cb = dinv[sb] * di;
        const float4 va = *(const float4*)(hw + (size_t)sa * Hd + l * 4);
        const float4 vb = *(const float4*)(hw + (size_t)sb * Hd + l * 4);
        acc.x = fmaf(va.x, ca, acc.x); acc.y = fmaf(va.y, ca, acc.y);
        acc.z = fmaf(va.z, ca, acc.z); acc.w = fmaf(va.w, ca, acc.w);
        acc.x = fmaf(vb.x, cb, acc.x); acc.y = fmaf(vb.y, cb, acc.y);
        acc.z = fmaf(vb.z, cb, acc.z); acc.w = fmaf(vb.w, cb, acc.w);
    }
    if (e < e1) {
        int sa = esrc[e];
        float ca = dinv[sa] * di;
        const float4 va = *(const float4*)(hw + (size_t)sa * Hd + l * 4);
        acc.x = fmaf(va.x, ca, acc.x); acc.y = fmaf(va.y, ca, acc.y);
        acc.z = fmaf(va.z, ca, acc.z); acc.w = fmaf(va.w, ca, acc.w);
    }
    *(float4*)(agg + (size_t)node * Hd + l * 4) = acc;

    // bn stats: block reduce over 16 node slots, sharded atomics (64 shards)
    __shared__ float ls[1024];
    ((float4*)ls)[threadIdx.x] = acc;   // layout: ls[g*64 + channel]
    __syncthreads();
    int t = threadIdx.x;
    if (t < 64) {
        float s = 0.f, s2 = 0.f;
#pragma unroll
        for (int gg = 0; gg < 16; gg++) {
            float v = ls[gg * 64 + t];
            s += v;
            s2 = fmaf(v, v, s2);
        }
        float* a = bnacc + (blockIdx.x & 63) * 128;
        atomicAdd(&a[t], s);
        atomicAdd(&a[64 + t], s2);
    }
}

__global__ void k_bnfinal(const float* __restrict__ acc, const float* __restrict__ gamma,
                          const float* __restrict__ beta, float* __restrict__ bnsc,
                          float* __restrict__ bnsh) {
    int c = threadIdx.x;
    if (c >= 64) return;
    float s = 0.f, s2 = 0.f;
    for (int sh = 0; sh < 64; sh++) {
        s  += acc[sh * 128 + c];
        s2 += acc[sh * 128 + 64 + c];
    }
    float mean = s / (float)Nn;
    float var = s2 / (float)Nn - mean * mean;
    var = fmaxf(var, 0.f);
    float sc = gamma[c] * rsqrtf(var + BN_EPS);
    bnsc[c] = sc;
    bnsh[c] = beta[c] - mean * sc;
}

// fused: final bn-apply + relu + residual + per-graph mean pool (no h4 write)
__global__ __launch_bounds__(1024) void k_poolF(const float* __restrict__ agg,
                                                const float* __restrict__ bnsc,
                                                const float* __restrict__ bnsh,
                                                const float* __restrict__ h,
                                                const int* __restrict__ gstart,
                                                float* __restrict__ pooled) {
    int g = blockIdx.x;
    int t = threadIdx.x;
    int ch = t & 63, sl = t >> 6;     // 16 slices
    float sc = bnsc[ch], shv = bnsh[ch];
    int n0 = gstart[g], n1 = gstart[g + 1];
    float s = 0.f;
    for (int n = n0 + sl; n < n1; n += 16) {
        float a  = agg[(size_t)n * Hd + ch];
        float ho = h[(size_t)n * Hd + ch];
        s += fmaxf(fmaf(a, sc, shv), 0.f) + ho;
    }
    __shared__ float ls[1024];
    ls[t] = s;
    __syncthreads();
    if (t < 64) {
        float acc = 0.f;
#pragma unroll
        for (int k = 0; k < 16; k++) acc += ls[k * 64 + t];
        float cnt = (float)(n1 - n0);
        pooled[g * Hd + t] = acc / fmaxf(cnt, 1.0f);
    }
}

__global__ __launch_bounds__(256) void k_head(const float* __restrict__ pooled,
                                              const float* __restrict__ w1,
                                              const float* __restrict__ b1,
                                              const float* __restrict__ w2,
                                              const float* __restrict__ b2,
                                              float* __restrict__ out) {
    __shared__ float sw1[Hd * 32], sw2[32], sb1[32];
    int t = threadIdx.x;
    for (int i = t; i < Hd * 32; i += 256) sw1[i] = w1[i];
    if (t < 32) { sw2[t] = w2[t]; sb1[t] = b1[t]; }
    __syncthreads();
    float acc2[32];
#pragma unroll
    for (int k = 0; k < 32; k++) acc2[k] = sb1[k];
    for (int j = 0; j < Hd; j++) {
        float pj = pooled[t * Hd + j];
#pragma unroll
        for (int k = 0; k < 32; k++) acc2[k] = fmaf(pj, sw1[j * 32 + k], acc2[k]);
    }
    float o = b2[0];
#pragma unroll
    for (int k = 0; k < 32; k++) o += fmaxf(acc2[k], 0.f) * sw2[k];
    out[t] = o;
}

// ---------------- launch ----------------

extern "C" void kernel_launch(void* const* d_in, const int* in_sizes, int n_in,
                              void* d_out, int out_size, void* d_ws, size_t ws_size,
                              hipStream_t stream) {
    const float* x       = (const float*)d_in[0];
    const int*   eidx    = (const int*)d_in[1];
    const int*   batch   = (const int*)d_in[2];
    const float* w_embed = (const float*)d_in[3];
    const float* b_embed = (const float*)d_in[4];
    const float* conv_W  = (const float*)d_in[5];
    const float* conv_b  = (const float*)d_in[6];
    const float* gamma   = (const float*)d_in[7];
    const float* beta    = (const float*)d_in[8];
    const float* w1      = (const float*)d_in[9];
    const float* b1      = (const float*)d_in[10];
    const float* w2      = (const float*)d_in[11];
    const float* b2      = (const float*)d_in[12];
    const int* src = eidx;
    const int* dst = eidx + Ne;

    char* p = (char*)d_ws;
    auto alloc = [&](size_t bytes) -> void* {
        void* r = (void*)p;
        p += (bytes + 255) / 256 * 256;
        return r;
    };
    float*    h       = (float*)alloc((size_t)Nn * Hd * 4);
    float*    hw      = (float*)alloc((size_t)Nn * Hd * 4);
    float*    agg     = (float*)alloc((size_t)Nn * Hd * 4);
    int*      deg     = (int*)alloc((size_t)Nn * 4);
    int*      row_off = (int*)alloc((size_t)(Nn + 1) * 4);
    float*    dinv    = (float*)alloc((size_t)Nn * 4);
    int*      bsum    = (int*)alloc(512 * 4);
    int*      esrc    = (int*)alloc((size_t)Ne * 4);
    unsigned* tpack   = (unsigned*)alloc((size_t)Ne * 4);
    int*      bcursor = (int*)alloc((size_t)NB * 4);
    float*    bnacc   = (float*)alloc((size_t)Ll * 64 * 128 * 4);
    float*    bnsc    = (float*)alloc(64 * 4);
    float*    bnsh    = (float*)alloc(64 * 4);
    float*    pooled  = (float*)alloc((size_t)Gg * Hd * 4);
    int*      gstart  = (int*)alloc((size_t)(Gg + 1) * 4);
    (void)ws_size; (void)in_sizes; (void)n_in; (void)out_size;

    const int NB_E = (Ne + 255) / 256;       // 6250
    const int NB_N = (Nn + 255) / 256;       // 391
    const int NB_G16 = (Nn + 15) / 16;       // 6250

    hipMemsetAsync(deg, 0, (size_t)Nn * 4, stream);
    hipMemsetAsync(bnacc, 0, (size_t)Ll * 64 * 128 * 4, stream);

    k_deg<<<NB_E, 256, 0, stream>>>(dst, deg);
    k_dinv<<<NB_N, 256, 0, stream>>>(deg, dinv);
    k_scanA<<<NB_N, 256, 0, stream>>>(deg, row_off, bsum);
    k_scanB<<<1, 512, 0, stream>>>(bsum, NB_N);
    k_scanC<<<NB_N, 256, 0, stream>>>(row_off, bsum);
    k_binit<<<(NB + 255) / 256, 256, 0, stream>>>(row_off, bcursor);
    k_bplace<<<NB_E, 256, 0, stream>>>(src, dst, bcursor, tpack);
    k_csr<<<NB, 256, 0, stream>>>(row_off, tpack, esrc);
    k_gstart<<<1, 256, 0, stream>>>(batch, gstart);

    k_embed_gemm<<<1024, 256, 0, stream>>>(x, w_embed, b_embed, conv_W, h, hw);

    for (int i = 0; i < Ll; i++) {
        if (i > 0)
            k_gemmF<<<1024, 256, 0, stream>>>(agg, bnsc, bnsh, h,
                                              conv_W + (size_t)i * Hd * Hd, hw);
        k_gatherS<<<NB_G16, 256, 0, stream>>>(hw, dinv, row_off, esrc,
                                              conv_b + (size_t)i * Hd, agg,
                                              bnacc + (size_t)i * 64 * 128);
        k_bnfinal<<<1, 64, 0, stream>>>(bnacc + (size_t)i * 64 * 128,
                                        gamma + (size_t)i * Hd,
                                        beta + (size_t)i * Hd, bnsc, bnsh);
    }

    k_poolF<<<Gg, 1024, 0, stream>>>(agg, bnsc, bnsh, h, gstart, pooled);
    k_head<<<1, 256, 0, stream>>>(pooled, w1, b1, w2, b2, (float*)d_out);
}

// Round 5
// 764.092 us; speedup vs baseline: 1.4651x; 1.4651x over previous
//
#include <hip/hip_runtime.h>

#define Nn 100000
#define Ne 1600000
#define Fi 32
#define Hd 64
#define Ll 4
#define Gg 256
#define BN_EPS 1e-5f
#define NPB 128                      // nodes per bucket
#define NBINS ((Nn + NPB - 1) / NPB) // 782 buckets
#define CHUNK 8192                   // edges per partition block
#define NBLK ((Ne + CHUNK - 1) / CHUNK) // 196 partition blocks
#define IDXW (NBINS + 2)             // 784, u16 row stride

// ---------------- setup kernels ----------------

__global__ void k_deg(const int* __restrict__ dst, int* __restrict__ deg) {
    int e = blockIdx.x * blockDim.x + threadIdx.x;
    if (e < Ne) atomicAdd(&deg[dst[e]], 1);
}

__global__ void k_dinv(const int* __restrict__ deg, float* __restrict__ dinv) {
    int n = blockIdx.x * blockDim.x + threadIdx.x;
    if (n < Nn) dinv[n] = rsqrtf((float)deg[n] + 1.0f);
}

// exclusive scan of deg into row_off (per-block), block sums to bsum
__global__ void k_scanA(const int* __restrict__ deg, int* __restrict__ row_off,
                        int* __restrict__ bsum) {
    __shared__ int s[256];
    int t = threadIdx.x;
    int i = blockIdx.x * 256 + t;
    int v = (i < Nn) ? deg[i] : 0;
    s[t] = v;
    __syncthreads();
    int x = v;
    for (int off = 1; off < 256; off <<= 1) {
        int u = (t >= off) ? s[t - off] : 0;
        __syncthreads();
        x += u;
        s[t] = x;
        __syncthreads();
    }
    if (i < Nn) row_off[i] = x - v;          // exclusive within block
    if (t == 255) bsum[blockIdx.x] = x;      // block total
}

__global__ void k_scanB(int* __restrict__ bsum, int nblk) {
    __shared__ int s[512];
    int t = threadIdx.x;
    int v = (t < nblk) ? bsum[t] : 0;
    s[t] = v;
    __syncthreads();
    int x = v;
    for (int off = 1; off < 512; off <<= 1) {
        int u = (t >= off) ? s[t - off] : 0;
        __syncthreads();
        x += u;
        s[t] = x;
        __syncthreads();
    }
    if (t < nblk) bsum[t] = x - v;           // exclusive block offsets
}

__global__ void k_scanC(int* __restrict__ row_off, const int* __restrict__ bsum) {
    int i = blockIdx.x * 256 + threadIdx.x;
    if (i < Nn) row_off[i] += bsum[blockIdx.x];
    if (i == 0) row_off[Nn] = Ne;
}

// block-major partition: each block bins its own 8192-edge chunk in LDS and
// writes it out contiguously (no global atomics, fully coalesced writes).
// tpack value = src(17b) | local_dst(7b)<<17 ; idx16 row = 783 offsets.
__global__ __launch_bounds__(256) void k_part(const int* __restrict__ src,
                                              const int* __restrict__ dst,
                                              unsigned* __restrict__ tpack,
                                              unsigned short* __restrict__ idx16) {
    __shared__ int hist[NBINS];
    __shared__ int lofs[NBINS + 1];
    __shared__ int wsum[256];
    __shared__ unsigned stage[CHUNK];
    int blk = blockIdx.x, t = threadIdx.x;
    int e0 = blk * CHUNK;
    int nval = min(CHUNK, Ne - e0);

    for (int i = t; i < NBINS; i += 256) hist[i] = 0;
    __syncthreads();
    for (int i = t; i < nval; i += 256)
        atomicAdd(&hist[dst[e0 + i] >> 7], 1);
    __syncthreads();

    // scan 782 bins: thread owns 4 consecutive bins, then scan thread sums
    int base = t * 4;
    int loc[4];
    int s = 0;
#pragma unroll
    for (int k = 0; k < 4; k++) {
        int b = base + k;
        int c = (b < NBINS) ? hist[b] : 0;
        loc[k] = s;
        s += c;
    }
    wsum[t] = s;
    __syncthreads();
    int x = s;
    for (int off = 1; off < 256; off <<= 1) {
        int u = (t >= off) ? wsum[t - off] : 0;
        __syncthreads();
        x += u;
        wsum[t] = x;
        __syncthreads();
    }
    int excl = x - s;
#pragma unroll
    for (int k = 0; k < 4; k++) {
        int b = base + k;
        if (b < NBINS) lofs[b] = excl + loc[k];
    }
    if (t == 0) lofs[NBINS] = nval;
    __syncthreads();

    // write u16 index row
    for (int i = t; i <= NBINS; i += 256)
        idx16[(size_t)blk * IDXW + i] = (unsigned short)lofs[i];

    // reuse hist as LDS cursors; stage bin-grouped
    for (int i = t; i < NBINS; i += 256) hist[i] = lofs[i];
    __syncthreads();
    for (int i = t; i < nval; i += 256) {
        int d = dst[e0 + i];
        int sv = src[e0 + i];
        int p = atomicAdd(&hist[d >> 7], 1);
        stage[p] = (unsigned)sv | ((unsigned)(d & (NPB - 1)) << 17);
    }
    __syncthreads();
    for (int i = t; i < nval; i += 256)
        tpack[(size_t)blk * CHUNK + i] = stage[i];
}

// per-bucket CSR build from the 196 runs listed in idx16
__global__ __launch_bounds__(256) void k_csr(const int* __restrict__ row_off,
                                             const unsigned* __restrict__ tpack,
                                             const unsigned short* __restrict__ idx16,
                                             int* __restrict__ esrc) {
    __shared__ int rstart[NBLK], rlen[NBLK];
    __shared__ int cnt[NPB], startv[NPB];
    int b = blockIdx.x, t = threadIdx.x;
    for (int r = t; r < NBLK; r += 256) {
        const unsigned short* row = idx16 + (size_t)r * IDXW;
        int s = row[b], e = row[b + 1];
        rstart[r] = r * CHUNK + s;
        rlen[r] = e - s;
    }
    if (t < NPB) cnt[t] = 0;
    __syncthreads();
    if (t < NBLK) {
        int rs = rstart[t], rl = rlen[t];
        for (int k = 0; k < rl; k++)
            atomicAdd(&cnt[tpack[rs + k] >> 17], 1);
    }
    __syncthreads();
    if (t < NPB) startv[t] = cnt[t];
    __syncthreads();
    for (int off = 1; off < NPB; off <<= 1) {
        int x = (t < NPB && t >= off) ? startv[t - off] : 0;
        __syncthreads();
        if (t < NPB) startv[t] += x;
        __syncthreads();
    }
    if (t < NPB) cnt[t] = startv[t] - cnt[t];   // exclusive start; reuse as cursor
    __syncthreads();
    int e0 = row_off[b * NPB];
    if (t < NBLK) {
        int rs = rstart[t], rl = rlen[t];
        for (int k = 0; k < rl; k++) {
            unsigned v = tpack[rs + k];
            int p = atomicAdd(&cnt[v >> 17], 1);
            esrc[e0 + p] = (int)(v & 0x1FFFFu);
        }
    }
}

// per-graph node ranges via binary search over sorted batch
__global__ void k_gstart(const int* __restrict__ batch, int* __restrict__ gstart) {
    int g = threadIdx.x;   // 256 threads
    int lo = 0, hi = Nn;
    while (lo < hi) {
        int mid = (lo + hi) >> 1;
        if (batch[mid] < g) lo = mid + 1; else hi = mid;
    }
    gstart[g] = lo;
    if (g == 0) gstart[Gg] = Nn;
}

// ---------------- dense kernels ----------------

// fused: h[n] = x[n]@we + be (kept in regs), write h, hw[n] = h[n]@W0, write hw
__global__ __launch_bounds__(256) void k_embed_gemm(const float* __restrict__ x,
                                                    const float* __restrict__ we,
                                                    const float* __restrict__ be,
                                                    const float* __restrict__ W,
                                                    float* __restrict__ h,
                                                    float* __restrict__ hw) {
    int lane = threadIdx.x & 63;
    int wid  = blockIdx.x * (blockDim.x >> 6) + (threadIdx.x >> 6);
    int nw   = gridDim.x * (blockDim.x >> 6);
    float wE[Fi];
#pragma unroll
    for (int k = 0; k < Fi; k++) wE[k] = we[k * Hd + lane];
    float b = be[lane];
    float w0[Hd];
#pragma unroll
    for (int k = 0; k < Hd; k++) w0[k] = W[k * Hd + lane];
    for (int n = wid; n < Nn; n += nw) {
        float xv = (lane < Fi) ? x[n * Fi + lane] : 0.f;
        float hn = b;
#pragma unroll
        for (int k = 0; k < Fi; k++) hn = fmaf(__shfl(xv, k, 64), wE[k], hn);
        h[n * Hd + lane] = hn;
        float acc = 0.f;
#pragma unroll
        for (int k = 0; k < Hd; k++) acc = fmaf(__shfl(hn, k, 64), w0[k], acc);
        hw[n * Hd + lane] = acc;
    }
}

// fused: hn = relu(agg*sc+sh) + h  (bn-apply of prev layer), write h, hw = hn@W
__global__ __launch_bounds__(256) void k_gemmF(const float* __restrict__ agg,
                                               const float* __restrict__ bnsc,
                                               const float* __restrict__ bnsh,
                                               float* __restrict__ h,
                                               const float* __restrict__ W,
                                               float* __restrict__ hw) {
    int lane = threadIdx.x & 63;
    int wid  = blockIdx.x * (blockDim.x >> 6) + (threadIdx.x >> 6);
    int nw   = gridDim.x * (blockDim.x >> 6);
    float sc = bnsc[lane], shv = bnsh[lane];
    float w[Hd];
#pragma unroll
    for (int k = 0; k < Hd; k++) w[k] = W[k * Hd + lane];
    for (int n = wid; n < Nn; n += nw) {
        float a  = agg[(size_t)n * Hd + lane];
        float ho = h[(size_t)n * Hd + lane];
        float hn = fmaxf(fmaf(a, sc, shv), 0.f) + ho;
        h[(size_t)n * Hd + lane] = hn;
        float acc = 0.f;
#pragma unroll
        for (int k = 0; k < Hd; k++) acc = fmaf(__shfl(hn, k, 64), w[k], acc);
        hw[(size_t)n * Hd + lane] = acc;
    }
}

// gather + on-the-fly coef + fused bn-stats (sharded atomics)
__global__ __launch_bounds__(256) void k_gatherS(const float* __restrict__ hw,
                                                 const float* __restrict__ dinv,
                                                 const int* __restrict__ row_off,
                                                 const int* __restrict__ esrc,
                                                 const float* __restrict__ bias,
                                                 float* __restrict__ agg,
                                                 float* __restrict__ bnacc) {
    int g = threadIdx.x >> 4;   // node slot in block (16)
    int l = threadIdx.x & 15;   // lane in node group
    int node = blockIdx.x * 16 + g;   // Nn % 16 == 0, always valid
    float di = dinv[node];
    float scl = di * di;
    const float* hrow = hw + (size_t)node * Hd + l * 4;
    float4 acc;
    acc.x = hrow[0] * scl; acc.y = hrow[1] * scl; acc.z = hrow[2] * scl; acc.w = hrow[3] * scl;
    const float* bp = bias + l * 4;
    acc.x += bp[0]; acc.y += bp[1]; acc.z += bp[2]; acc.w += bp[3];

    int e = row_off[node], e1 = row_off[node + 1];
    for (; e + 1 < e1; e += 2) {
        int sa = esrc[e], sb = esrc[e + 1];
        float ca = dinv[sa] * di, cb = dinv[sb] * di;
        const float4 va = *(const float4*)(hw + (size_t)sa * Hd + l * 4);
        const float4 vb = *(const float4*)(hw + (size_t)sb * Hd + l * 4);
        acc.x = fmaf(va.x, ca, acc.x); acc.y = fmaf(va.y, ca, acc.y);
        acc.z = fmaf(va.z, ca, acc.z); acc.w = fmaf(va.w, ca, acc.w);
        acc.x = fmaf(vb.x, cb, acc.x); acc.y = fmaf(vb.y, cb, acc.y);
        acc.z = fmaf(vb.z, cb, acc.z); acc.w = fmaf(vb.w, cb, acc.w);
    }
    if (e < e1) {
        int sa = esrc[e];
        float ca = dinv[sa] * di;
        const float4 va = *(const float4*)(hw + (size_t)sa * Hd + l * 4);
        acc.x = fmaf(va.x, ca, acc.x); acc.y = fmaf(va.y, ca, acc.y);
        acc.z = fmaf(va.z, ca, acc.z); acc.w = fmaf(va.w, ca, acc.w);
    }
    *(float4*)(agg + (size_t)node * Hd + l * 4) = acc;

    // bn stats: block reduce over 16 node slots, sharded atomics (64 shards)
    __shared__ float ls[1024];
    ((float4*)ls)[threadIdx.x] = acc;   // layout: ls[g*64 + channel]
    __syncthreads();
    int t = threadIdx.x;
    if (t < 64) {
        float s = 0.f, s2 = 0.f;
#pragma unroll
        for (int gg = 0; gg < 16; gg++) {
            float v = ls[gg * 64 + t];
            s += v;
            s2 = fmaf(v, v, s2);
        }
        float* a = bnacc + (blockIdx.x & 63) * 128;
        atomicAdd(&a[t], s);
        atomicAdd(&a[64 + t], s2);
    }
}

__global__ void k_bnfinal(const float* __restrict__ acc, const float* __restrict__ gamma,
                          const float* __restrict__ beta, float* __restrict__ bnsc,
                          float* __restrict__ bnsh) {
    int c = threadIdx.x;
    if (c >= 64) return;
    float s = 0.f, s2 = 0.f;
    for (int sh = 0; sh < 64; sh++) {
        s  += acc[sh * 128 + c];
        s2 += acc[sh * 128 + 64 + c];
    }
    float mean = s / (float)Nn;
    float var = s2 / (float)Nn - mean * mean;
    var = fmaxf(var, 0.f);
    float sc = gamma[c] * rsqrtf(var + BN_EPS);
    bnsc[c] = sc;
    bnsh[c] = beta[c] - mean * sc;
}

// fused: final bn-apply + relu + residual + per-graph mean pool (no h4 write)
__global__ __launch_bounds__(1024) void k_poolF(const float* __restrict__ agg,
                                                const float* __restrict__ bnsc,
                                                const float* __restrict__ bnsh,
                                                const float* __restrict__ h,
                                                const int* __restrict__ gstart,
                                                float* __restrict__ pooled) {
    int g = blockIdx.x;
    int t = threadIdx.x;
    int ch = t & 63, sl = t >> 6;     // 16 slices
    float sc = bnsc[ch], shv = bnsh[ch];
    int n0 = gstart[g], n1 = gstart[g + 1];
    float s = 0.f;
    for (int n = n0 + sl; n < n1; n += 16) {
        float a  = agg[(size_t)n * Hd + ch];
        float ho = h[(size_t)n * Hd + ch];
        s += fmaxf(fmaf(a, sc, shv), 0.f) + ho;
    }
    __shared__ float ls[1024];
    ls[t] = s;
    __syncthreads();
    if (t < 64) {
        float acc = 0.f;
#pragma unroll
        for (int k = 0; k < 16; k++) acc += ls[k * 64 + t];
        float cnt = (float)(n1 - n0);
        pooled[g * Hd + t] = acc / fmaxf(cnt, 1.0f);
    }
}

__global__ __launch_bounds__(256) void k_head(const float* __restrict__ pooled,
                                              const float* __restrict__ w1,
                                              const float* __restrict__ b1,
                                              const float* __restrict__ w2,
                                              const float* __restrict__ b2,
                                              float* __restrict__ out) {
    __shared__ float sw1[Hd * 32], sw2[32], sb1[32];
    int t = threadIdx.x;
    for (int i = t; i < Hd * 32; i += 256) sw1[i] = w1[i];
    if (t < 32) { sw2[t] = w2[t]; sb1[t] = b1[t]; }
    __syncthreads();
    float acc2[32];
#pragma unroll
    for (int k = 0; k < 32; k++) acc2[k] = sb1[k];
    for (int j = 0; j < Hd; j++) {
        float pj = pooled[t * Hd + j];
#pragma unroll
        for (int k = 0; k < 32; k++) acc2[k] = fmaf(pj, sw1[j * 32 + k], acc2[k]);
    }
    float o = b2[0];
#pragma unroll
    for (int k = 0; k < 32; k++) o += fmaxf(acc2[k], 0.f) * sw2[k];
    out[t] = o;
}

// ---------------- launch ----------------

extern "C" void kernel_launch(void* const* d_in, const int* in_sizes, int n_in,
                              void* d_out, int out_size, void* d_ws, size_t ws_size,
                              hipStream_t stream) {
    const float* x       = (const float*)d_in[0];
    const int*   eidx    = (const int*)d_in[1];
    const int*   batch   = (const int*)d_in[2];
    const float* w_embed = (const float*)d_in[3];
    const float* b_embed = (const float*)d_in[4];
    const float* conv_W  = (const float*)d_in[5];
    const float* conv_b  = (const float*)d_in[6];
    const float* gamma   = (const float*)d_in[7];
    const float* beta    = (const float*)d_in[8];
    const float* w1      = (const float*)d_in[9];
    const float* b1      = (const float*)d_in[10];
    const float* w2      = (const float*)d_in[11];
    const float* b2      = (const float*)d_in[12];
    const int* src = eidx;
    const int* dst = eidx + Ne;

    char* p = (char*)d_ws;
    auto alloc = [&](size_t bytes) -> void* {
        void* r = (void*)p;
        p += (bytes + 255) / 256 * 256;
        return r;
    };
    float*    h       = (float*)alloc((size_t)Nn * Hd * 4);
    float*    hw      = (float*)alloc((size_t)Nn * Hd * 4);
    float*    agg     = (float*)alloc((size_t)Nn * Hd * 4);
    int*      deg     = (int*)alloc((size_t)Nn * 4);
    int*      row_off = (int*)alloc((size_t)(Nn + 1) * 4);
    float*    dinv    = (float*)alloc((size_t)Nn * 4);
    int*      bsum    = (int*)alloc(512 * 4);
    int*      esrc    = (int*)alloc((size_t)Ne * 4);
    unsigned* tpack   = (unsigned*)alloc((size_t)NBLK * CHUNK * 4);
    unsigned short* idx16 = (unsigned short*)alloc((size_t)NBLK * IDXW * 2);
    float*    bnacc   = (float*)alloc((size_t)Ll * 64 * 128 * 4);
    float*    bnsc    = (float*)alloc(64 * 4);
    float*    bnsh    = (float*)alloc(64 * 4);
    float*    pooled  = (float*)alloc((size_t)Gg * Hd * 4);
    int*      gstart  = (int*)alloc((size_t)(Gg + 1) * 4);
    (void)ws_size; (void)in_sizes; (void)n_in; (void)out_size;

    const int NB_E = (Ne + 255) / 256;       // 6250
    const int NB_N = (Nn + 255) / 256;       // 391
    const int NB_G16 = (Nn + 15) / 16;       // 6250

    hipMemsetAsync(deg, 0, (size_t)Nn * 4, stream);
    hipMemsetAsync(bnacc, 0, (size_t)Ll * 64 * 128 * 4, stream);

    k_deg<<<NB_E, 256, 0, stream>>>(dst, deg);
    k_dinv<<<NB_N, 256, 0, stream>>>(deg, dinv);
    k_scanA<<<NB_N, 256, 0, stream>>>(deg, row_off, bsum);
    k_scanB<<<1, 512, 0, stream>>>(bsum, NB_N);
    k_scanC<<<NB_N, 256, 0, stream>>>(row_off, bsum);
    k_part<<<NBLK, 256, 0, stream>>>(src, dst, tpack, idx16);
    k_csr<<<NBINS, 256, 0, stream>>>(row_off, tpack, idx16, esrc);
    k_gstart<<<1, 256, 0, stream>>>(batch, gstart);

    k_embed_gemm<<<1024, 256, 0, stream>>>(x, w_embed, b_embed, conv_W, h, hw);

    for (int i = 0; i < Ll; i++) {
        if (i > 0)
            k_gemmF<<<1024, 256, 0, stream>>>(agg, bnsc, bnsh, h,
                                              conv_W + (size_t)i * Hd * Hd, hw);
        k_gatherS<<<NB_G16, 256, 0, stream>>>(hw, dinv, row_off, esrc,
                                              conv_b + (size_t)i * Hd, agg,
                                              bnacc + (size_t)i * 64 * 128);
        k_bnfinal<<<1, 64, 0, stream>>>(bnacc + (size_t)i * 64 * 128,
                                        gamma + (size_t)i * Hd,
                                        beta + (size_t)i * Hd, bnsc, bnsh);
    }

    k_poolF<<<Gg, 1024, 0, stream>>>(agg, bnsc, bnsh, h, gstart, pooled);
    k_head<<<1, 256, 0, stream>>>(pooled, w1, b1, w2, b2, (float*)d_out);
}

// Round 6
// 633.512 us; speedup vs baseline: 1.7671x; 1.2061x over previous
//
#include <hip/hip_runtime.h>

#define Nn 100000
#define Ne 1600000
#define Fi 32
#define Hd 64
#define Ll 4
#define Gg 256
#define BN_EPS 1e-5f
#define NPB 128                      // nodes per bucket
#define NBINS ((Nn + NPB - 1) / NPB) // 782 buckets
#define CHUNK 8192                   // edges per partition block
#define NBLK ((Ne + CHUNK - 1) / CHUNK) // 196 partition blocks
#define IDXW (NBINS + 2)             // 784, u16 row stride
#define TPAD 68                      // padded LDS row stride for 64-wide tiles
#define XPAD 36                      // padded LDS row stride for 32-wide tiles
#define NGB ((Nn + 63) / 64)         // 1563 GEMM tiles

// ---------------- setup kernels ----------------

__global__ void k_deg(const int* __restrict__ dst, int* __restrict__ deg) {
    int e = blockIdx.x * blockDim.x + threadIdx.x;
    if (e < Ne) atomicAdd(&deg[dst[e]], 1);
}

__global__ void k_dinv(const int* __restrict__ deg, float* __restrict__ dinv) {
    int n = blockIdx.x * blockDim.x + threadIdx.x;
    if (n < Nn) dinv[n] = rsqrtf((float)deg[n] + 1.0f);
}

__global__ void k_scanA(const int* __restrict__ deg, int* __restrict__ row_off,
                        int* __restrict__ bsum) {
    __shared__ int s[256];
    int t = threadIdx.x;
    int i = blockIdx.x * 256 + t;
    int v = (i < Nn) ? deg[i] : 0;
    s[t] = v;
    __syncthreads();
    int x = v;
    for (int off = 1; off < 256; off <<= 1) {
        int u = (t >= off) ? s[t - off] : 0;
        __syncthreads();
        x += u;
        s[t] = x;
        __syncthreads();
    }
    if (i < Nn) row_off[i] = x - v;
    if (t == 255) bsum[blockIdx.x] = x;
}

__global__ void k_scanB(int* __restrict__ bsum, int nblk) {
    __shared__ int s[512];
    int t = threadIdx.x;
    int v = (t < nblk) ? bsum[t] : 0;
    s[t] = v;
    __syncthreads();
    int x = v;
    for (int off = 1; off < 512; off <<= 1) {
        int u = (t >= off) ? s[t - off] : 0;
        __syncthreads();
        x += u;
        s[t] = x;
        __syncthreads();
    }
    if (t < nblk) bsum[t] = x - v;
}

__global__ void k_scanC(int* __restrict__ row_off, const int* __restrict__ bsum) {
    int i = blockIdx.x * 256 + threadIdx.x;
    if (i < Nn) row_off[i] += bsum[blockIdx.x];
    if (i == 0) row_off[Nn] = Ne;
}

// block-major partition (no global atomics, coalesced writes)
__global__ __launch_bounds__(256) void k_part(const int* __restrict__ src,
                                              const int* __restrict__ dst,
                                              unsigned* __restrict__ tpack,
                                              unsigned short* __restrict__ idx16) {
    __shared__ int hist[NBINS];
    __shared__ int lofs[NBINS + 1];
    __shared__ int wsum[256];
    __shared__ unsigned stage[CHUNK];
    int blk = blockIdx.x, t = threadIdx.x;
    int e0 = blk * CHUNK;
    int nval = min(CHUNK, Ne - e0);

    for (int i = t; i < NBINS; i += 256) hist[i] = 0;
    __syncthreads();
    for (int i = t; i < nval; i += 256)
        atomicAdd(&hist[dst[e0 + i] >> 7], 1);
    __syncthreads();

    int base = t * 4;
    int loc[4];
    int s = 0;
#pragma unroll
    for (int k = 0; k < 4; k++) {
        int b = base + k;
        int c = (b < NBINS) ? hist[b] : 0;
        loc[k] = s;
        s += c;
    }
    wsum[t] = s;
    __syncthreads();
    int x = s;
    for (int off = 1; off < 256; off <<= 1) {
        int u = (t >= off) ? wsum[t - off] : 0;
        __syncthreads();
        x += u;
        wsum[t] = x;
        __syncthreads();
    }
    int excl = x - s;
#pragma unroll
    for (int k = 0; k < 4; k++) {
        int b = base + k;
        if (b < NBINS) lofs[b] = excl + loc[k];
    }
    if (t == 0) lofs[NBINS] = nval;
    __syncthreads();

    for (int i = t; i <= NBINS; i += 256)
        idx16[(size_t)blk * IDXW + i] = (unsigned short)lofs[i];

    for (int i = t; i < NBINS; i += 256) hist[i] = lofs[i];
    __syncthreads();
    for (int i = t; i < nval; i += 256) {
        int d = dst[e0 + i];
        int sv = src[e0 + i];
        int p = atomicAdd(&hist[d >> 7], 1);
        stage[p] = (unsigned)sv | ((unsigned)(d & (NPB - 1)) << 17);
    }
    __syncthreads();
    for (int i = t; i < nval; i += 256)
        tpack[(size_t)blk * CHUNK + i] = stage[i];
}

// per-bucket CSR build
__global__ __launch_bounds__(256) void k_csr(const int* __restrict__ row_off,
                                             const unsigned* __restrict__ tpack,
                                             const unsigned short* __restrict__ idx16,
                                             int* __restrict__ esrc) {
    __shared__ int rstart[NBLK], rlen[NBLK];
    __shared__ int cnt[NPB], startv[NPB];
    int b = blockIdx.x, t = threadIdx.x;
    for (int r = t; r < NBLK; r += 256) {
        const unsigned short* row = idx16 + (size_t)r * IDXW;
        int s = row[b], e = row[b + 1];
        rstart[r] = r * CHUNK + s;
        rlen[r] = e - s;
    }
    if (t < NPB) cnt[t] = 0;
    __syncthreads();
    if (t < NBLK) {
        int rs = rstart[t], rl = rlen[t];
        for (int k = 0; k < rl; k++)
            atomicAdd(&cnt[tpack[rs + k] >> 17], 1);
    }
    __syncthreads();
    if (t < NPB) startv[t] = cnt[t];
    __syncthreads();
    for (int off = 1; off < NPB; off <<= 1) {
        int x = (t < NPB && t >= off) ? startv[t - off] : 0;
        __syncthreads();
        if (t < NPB) startv[t] += x;
        __syncthreads();
    }
    if (t < NPB) cnt[t] = startv[t] - cnt[t];
    __syncthreads();
    int e0 = row_off[b * NPB];
    if (t < NBLK) {
        int rs = rstart[t], rl = rlen[t];
        for (int k = 0; k < rl; k++) {
            unsigned v = tpack[rs + k];
            int p = atomicAdd(&cnt[v >> 17], 1);
            esrc[e0 + p] = (int)(v & 0x1FFFFu);
        }
    }
}

__global__ void k_gstart(const int* __restrict__ batch, int* __restrict__ gstart) {
    int g = threadIdx.x;
    int lo = 0, hi = Nn;
    while (lo < hi) {
        int mid = (lo + hi) >> 1;
        if (batch[mid] < g) lo = mid + 1; else hi = mid;
    }
    gstart[g] = lo;
    if (g == 0) gstart[Gg] = Nn;
}

// ---------------- tiled GEMM kernels ----------------

// 4x4 micro-tile FMA: acc[r][c] += a_r[q] * w_q[c]
#define MT_FMA(AV, W0, W1, W2, W3, R)                                          \
    acc[R][0] = fmaf(AV.x, W0.x, acc[R][0]);                                   \
    acc[R][0] = fmaf(AV.y, W1.x, acc[R][0]);                                   \
    acc[R][0] = fmaf(AV.z, W2.x, acc[R][0]);                                   \
    acc[R][0] = fmaf(AV.w, W3.x, acc[R][0]);                                   \
    acc[R][1] = fmaf(AV.x, W0.y, acc[R][1]);                                   \
    acc[R][1] = fmaf(AV.y, W1.y, acc[R][1]);                                   \
    acc[R][1] = fmaf(AV.z, W2.y, acc[R][1]);                                   \
    acc[R][1] = fmaf(AV.w, W3.y, acc[R][1]);                                   \
    acc[R][2] = fmaf(AV.x, W0.z, acc[R][2]);                                   \
    acc[R][2] = fmaf(AV.y, W1.z, acc[R][2]);                                   \
    acc[R][2] = fmaf(AV.z, W2.z, acc[R][2]);                                   \
    acc[R][2] = fmaf(AV.w, W3.z, acc[R][2]);                                   \
    acc[R][3] = fmaf(AV.x, W0.w, acc[R][3]);                                   \
    acc[R][3] = fmaf(AV.y, W1.w, acc[R][3]);                                   \
    acc[R][3] = fmaf(AV.z, W2.w, acc[R][3]);                                   \
    acc[R][3] = fmaf(AV.w, W3.w, acc[R][3]);

// fused: hn = relu(agg*sc+sh)+h (write h), hw = hn@W (write hw). 64-node tile.
__global__ __launch_bounds__(256) void k_gemmF2(const float* __restrict__ agg,
                                                const float* __restrict__ bnsc,
                                                const float* __restrict__ bnsh,
                                                float* __restrict__ h,
                                                const float* __restrict__ W,
                                                float* __restrict__ hw) {
    __shared__ float hs[64 * TPAD];
    __shared__ float ws[64 * 64];
    int t = threadIdx.x;
    int n0 = blockIdx.x * 64;

    for (int f = t; f < 1024; f += 256)
        ((float4*)ws)[f] = ((const float4*)W)[f];

    // stage hn: f indexes float4s; row = f>>4, c4 = (f&15)*4
    for (int f = t; f < 1024; f += 256) {
        int row = f >> 4, c4 = (f & 15) * 4;
        int node = n0 + row;
        if (node < Nn) {
            float4 a  = *(const float4*)(agg + (size_t)node * Hd + c4);
            float4 ho = *(const float4*)(h + (size_t)node * Hd + c4);
            float4 sc = ((const float4*)bnsc)[f & 15];
            float4 sh = ((const float4*)bnsh)[f & 15];
            float4 r4;
            r4.x = fmaxf(fmaf(a.x, sc.x, sh.x), 0.f) + ho.x;
            r4.y = fmaxf(fmaf(a.y, sc.y, sh.y), 0.f) + ho.y;
            r4.z = fmaxf(fmaf(a.z, sc.z, sh.z), 0.f) + ho.z;
            r4.w = fmaxf(fmaf(a.w, sc.w, sh.w), 0.f) + ho.w;
            *(float4*)(h + (size_t)node * Hd + c4) = r4;
            *(float4*)&hs[row * TPAD + c4] = r4;
        } else {
            *(float4*)&hs[row * TPAD + c4] = make_float4(0.f, 0.f, 0.f, 0.f);
        }
    }
    __syncthreads();

    int i = t >> 4, j = t & 15;
    float acc[4][4] = {};
#pragma unroll
    for (int k = 0; k < 64; k += 4) {
        float4 w0 = *(const float4*)&ws[(k + 0) * 64 + 4 * j];
        float4 w1 = *(const float4*)&ws[(k + 1) * 64 + 4 * j];
        float4 w2 = *(const float4*)&ws[(k + 2) * 64 + 4 * j];
        float4 w3 = *(const float4*)&ws[(k + 3) * 64 + 4 * j];
        float4 a0 = *(const float4*)&hs[(4 * i + 0) * TPAD + k];
        float4 a1 = *(const float4*)&hs[(4 * i + 1) * TPAD + k];
        float4 a2 = *(const float4*)&hs[(4 * i + 2) * TPAD + k];
        float4 a3 = *(const float4*)&hs[(4 * i + 3) * TPAD + k];
        MT_FMA(a0, w0, w1, w2, w3, 0)
        MT_FMA(a1, w0, w1, w2, w3, 1)
        MT_FMA(a2, w0, w1, w2, w3, 2)
        MT_FMA(a3, w0, w1, w2, w3, 3)
    }
#pragma unroll
    for (int r = 0; r < 4; r++) {
        int node = n0 + 4 * i + r;
        if (node < Nn)
            *(float4*)(hw + (size_t)node * Hd + 4 * j) =
                make_float4(acc[r][0], acc[r][1], acc[r][2], acc[r][3]);
    }
}

// fused: h = x@we+be (write h), hw = h@W0 (write hw). 64-node tile.
__global__ __launch_bounds__(256) void k_embed_gemm2(const float* __restrict__ x,
                                                     const float* __restrict__ we,
                                                     const float* __restrict__ be,
                                                     const float* __restrict__ W,
                                                     float* __restrict__ h,
                                                     float* __restrict__ hw) {
    __shared__ float xs[64 * XPAD];
    __shared__ float wes[32 * 64];
    __shared__ float hs[64 * TPAD];
    __shared__ float ws[64 * 64];
    __shared__ float bes[64];
    int t = threadIdx.x;
    int n0 = blockIdx.x * 64;

    for (int f = t; f < 512; f += 256)
        ((float4*)wes)[f] = ((const float4*)we)[f];
    for (int f = t; f < 1024; f += 256)
        ((float4*)ws)[f] = ((const float4*)W)[f];
    if (t < 64) bes[t] = be[t];

    for (int f = t; f < 512; f += 256) {
        int row = f >> 3, c4 = (f & 7) * 4;
        int node = n0 + row;
        float4 v = (node < Nn) ? *(const float4*)(x + (size_t)node * Fi + c4)
                               : make_float4(0.f, 0.f, 0.f, 0.f);
        *(float4*)&xs[row * XPAD + c4] = v;
    }
    __syncthreads();

    int i = t >> 4, j = t & 15;
    {
        float acc[4][4];
#pragma unroll
        for (int r = 0; r < 4; r++)
#pragma unroll
            for (int c = 0; c < 4; c++) acc[r][c] = bes[4 * j + c];
#pragma unroll
        for (int k = 0; k < 32; k += 4) {
            float4 w0 = *(const float4*)&wes[(k + 0) * 64 + 4 * j];
            float4 w1 = *(const float4*)&wes[(k + 1) * 64 + 4 * j];
            float4 w2 = *(const float4*)&wes[(k + 2) * 64 + 4 * j];
            float4 w3 = *(const float4*)&wes[(k + 3) * 64 + 4 * j];
            float4 a0 = *(const float4*)&xs[(4 * i + 0) * XPAD + k];
            float4 a1 = *(const float4*)&xs[(4 * i + 1) * XPAD + k];
            float4 a2 = *(const float4*)&xs[(4 * i + 2) * XPAD + k];
            float4 a3 = *(const float4*)&xs[(4 * i + 3) * XPAD + k];
            MT_FMA(a0, w0, w1, w2, w3, 0)
            MT_FMA(a1, w0, w1, w2, w3, 1)
            MT_FMA(a2, w0, w1, w2, w3, 2)
            MT_FMA(a3, w0, w1, w2, w3, 3)
        }
#pragma unroll
        for (int r = 0; r < 4; r++) {
            int node = n0 + 4 * i + r;
            float4 hv = make_float4(acc[r][0], acc[r][1], acc[r][2], acc[r][3]);
            *(float4*)&hs[(4 * i + r) * TPAD + 4 * j] = hv;
            if (node < Nn)
                *(float4*)(h + (size_t)node * Hd + 4 * j) = hv;
        }
    }
    __syncthreads();
    {
        float acc[4][4] = {};
#pragma unroll
        for (int k = 0; k < 64; k += 4) {
            float4 w0 = *(const float4*)&ws[(k + 0) * 64 + 4 * j];
            float4 w1 = *(const float4*)&ws[(k + 1) * 64 + 4 * j];
            float4 w2 = *(const float4*)&ws[(k + 2) * 64 + 4 * j];
            float4 w3 = *(const float4*)&ws[(k + 3) * 64 + 4 * j];
            float4 a0 = *(const float4*)&hs[(4 * i + 0) * TPAD + k];
            float4 a1 = *(const float4*)&hs[(4 * i + 1) * TPAD + k];
            float4 a2 = *(const float4*)&hs[(4 * i + 2) * TPAD + k];
            float4 a3 = *(const float4*)&hs[(4 * i + 3) * TPAD + k];
            MT_FMA(a0, w0, w1, w2, w3, 0)
            MT_FMA(a1, w0, w1, w2, w3, 1)
            MT_FMA(a2, w0, w1, w2, w3, 2)
            MT_FMA(a3, w0, w1, w2, w3, 3)
        }
#pragma unroll
        for (int r = 0; r < 4; r++) {
            int node = n0 + 4 * i + r;
            if (node < Nn)
                *(float4*)(hw + (size_t)node * Hd + 4 * j) =
                    make_float4(acc[r][0], acc[r][1], acc[r][2], acc[r][3]);
        }
    }
}

// ---------------- gather / bn / pool / head ----------------

__global__ __launch_bounds__(256) void k_gatherS(const float* __restrict__ hw,
                                                 const float* __restrict__ dinv,
                                                 const int* __restrict__ row_off,
                                                 const int* __restrict__ esrc,
                                                 const float* __restrict__ bias,
                                                 float* __restrict__ agg,
                                                 float* __restrict__ bnacc) {
    int g = threadIdx.x >> 4;
    int l = threadIdx.x & 15;
    int node = blockIdx.x * 16 + g;
    float di = dinv[node];
    float scl = di * di;
    const float* hrow = hw + (size_t)node * Hd + l * 4;
    float4 acc;
    acc.x = hrow[0] * scl; acc.y = hrow[1] * scl; acc.z = hrow[2] * scl; acc.w = hrow[3] * scl;
    const float* bp = bias + l * 4;
    acc.x += bp[0]; acc.y += bp[1]; acc.z += bp[2]; acc.w += bp[3];

    int e = row_off[node], e1 = row_off[node + 1];
    for (; e + 1 < e1; e += 2) {
        int sa = esrc[e], sb = esrc[e + 1];
        float ca = dinv[sa] * di, cb = dinv[sb] * di;
        const float4 va = *(const float4*)(hw + (size_t)sa * Hd + l * 4);
        const float4 vb = *(const float4*)(hw + (size_t)sb * Hd + l * 4);
        acc.x = fmaf(va.x, ca, acc.x); acc.y = fmaf(va.y, ca, acc.y);
        acc.z = fmaf(va.z, ca, acc.z); acc.w = fmaf(va.w, ca, acc.w);
        acc.x = fmaf(vb.x, cb, acc.x); acc.y = fmaf(vb.y, cb, acc.y);
        acc.z = fmaf(vb.z, cb, acc.z); acc.w = fmaf(vb.w, cb, acc.w);
    }
    if (e < e1) {
        int sa = esrc[e];
        float ca = dinv[sa] * di;
        const float4 va = *(const float4*)(hw + (size_t)sa * Hd + l * 4);
        acc.x = fmaf(va.x, ca, acc.x); acc.y = fmaf(va.y, ca, acc.y);
        acc.z = fmaf(va.z, ca, acc.z); acc.w = fmaf(va.w, ca, acc.w);
    }
    *(float4*)(agg + (size_t)node * Hd + l * 4) = acc;

    __shared__ float ls[1024];
    ((float4*)ls)[threadIdx.x] = acc;
    __syncthreads();
    int t = threadIdx.x;
    if (t < 64) {
        float s = 0.f, s2 = 0.f;
#pragma unroll
        for (int gg = 0; gg < 16; gg++) {
            float v = ls[gg * 64 + t];
            s += v;
            s2 = fmaf(v, v, s2);
        }
        float* a = bnacc + (blockIdx.x & 63) * 128;
        atomicAdd(&a[t], s);
        atomicAdd(&a[64 + t], s2);
    }
}

__global__ void k_bnfinal(const float* __restrict__ acc, const float* __restrict__ gamma,
                          const float* __restrict__ beta, float* __restrict__ bnsc,
                          float* __restrict__ bnsh) {
    int c = threadIdx.x;
    if (c >= 64) return;
    float s = 0.f, s2 = 0.f;
    for (int sh = 0; sh < 64; sh++) {
        s  += acc[sh * 128 + c];
        s2 += acc[sh * 128 + 64 + c];
    }
    float mean = s / (float)Nn;
    float var = s2 / (float)Nn - mean * mean;
    var = fmaxf(var, 0.f);
    float sc = gamma[c] * rsqrtf(var + BN_EPS);
    bnsc[c] = sc;
    bnsh[c] = beta[c] - mean * sc;
}

__global__ __launch_bounds__(1024) void k_poolF(const float* __restrict__ agg,
                                                const float* __restrict__ bnsc,
                                                const float* __restrict__ bnsh,
                                                const float* __restrict__ h,
                                                const int* __restrict__ gstart,
                                                float* __restrict__ pooled) {
    int g = blockIdx.x;
    int t = threadIdx.x;
    int ch = t & 63, sl = t >> 6;
    float sc = bnsc[ch], shv = bnsh[ch];
    int n0 = gstart[g], n1 = gstart[g + 1];
    float s = 0.f;
    for (int n = n0 + sl; n < n1; n += 16) {
        float a  = agg[(size_t)n * Hd + ch];
        float ho = h[(size_t)n * Hd + ch];
        s += fmaxf(fmaf(a, sc, shv), 0.f) + ho;
    }
    __shared__ float ls[1024];
    ls[t] = s;
    __syncthreads();
    if (t < 64) {
        float acc = 0.f;
#pragma unroll
        for (int k = 0; k < 16; k++) acc += ls[k * 64 + t];
        float cnt = (float)(n1 - n0);
        pooled[g * Hd + t] = acc / fmaxf(cnt, 1.0f);
    }
}

__global__ __launch_bounds__(256) void k_head(const float* __restrict__ pooled,
                                              const float* __restrict__ w1,
                                              const float* __restrict__ b1,
                                              const float* __restrict__ w2,
                                              const float* __restrict__ b2,
                                              float* __restrict__ out) {
    __shared__ float sw1[Hd * 32], sw2[32], sb1[32];
    int t = threadIdx.x;
    for (int i = t; i < Hd * 32; i += 256) sw1[i] = w1[i];
    if (t < 32) { sw2[t] = w2[t]; sb1[t] = b1[t]; }
    __syncthreads();
    float acc2[32];
#pragma unroll
    for (int k = 0; k < 32; k++) acc2[k] = sb1[k];
    for (int j = 0; j < Hd; j++) {
        float pj = pooled[t * Hd + j];
#pragma unroll
        for (int k = 0; k < 32; k++) acc2[k] = fmaf(pj, sw1[j * 32 + k], acc2[k]);
    }
    float o = b2[0];
#pragma unroll
    for (int k = 0; k < 32; k++) o += fmaxf(acc2[k], 0.f) * sw2[k];
    out[t] = o;
}

// ---------------- launch ----------------

extern "C" void kernel_launch(void* const* d_in, const int* in_sizes, int n_in,
                              void* d_out, int out_size, void* d_ws, size_t ws_size,
                              hipStream_t stream) {
    const float* x       = (const float*)d_in[0];
    const int*   eidx    = (const int*)d_in[1];
    const int*   batch   = (const int*)d_in[2];
    const float* w_embed = (const float*)d_in[3];
    const float* b_embed = (const float*)d_in[4];
    const float* conv_W  = (const float*)d_in[5];
    const float* conv_b  = (const float*)d_in[6];
    const float* gamma   = (const float*)d_in[7];
    const float* beta    = (const float*)d_in[8];
    const float* w1      = (const float*)d_in[9];
    const float* b1      = (const float*)d_in[10];
    const float* w2      = (const float*)d_in[11];
    const float* b2      = (const float*)d_in[12];
    const int* src = eidx;
    const int* dst = eidx + Ne;

    char* p = (char*)d_ws;
    auto alloc = [&](size_t bytes) -> void* {
        void* r = (void*)p;
        p += (bytes + 255) / 256 * 256;
        return r;
    };
    float*    h       = (float*)alloc((size_t)Nn * Hd * 4);
    float*    hw      = (float*)alloc((size_t)Nn * Hd * 4);
    float*    agg     = (float*)alloc((size_t)Nn * Hd * 4);
    int*      deg     = (int*)alloc((size_t)Nn * 4);
    int*      row_off = (int*)alloc((size_t)(Nn + 1) * 4);
    float*    dinv    = (float*)alloc((size_t)Nn * 4);
    int*      bsum    = (int*)alloc(512 * 4);
    int*      esrc    = (int*)alloc((size_t)Ne * 4);
    unsigned* tpack   = (unsigned*)alloc((size_t)NBLK * CHUNK * 4);
    unsigned short* idx16 = (unsigned short*)alloc((size_t)NBLK * IDXW * 2);
    float*    bnacc   = (float*)alloc((size_t)Ll * 64 * 128 * 4);
    float*    bnsc    = (float*)alloc(64 * 4);
    float*    bnsh    = (float*)alloc(64 * 4);
    float*    pooled  = (float*)alloc((size_t)Gg * Hd * 4);
    int*      gstart  = (int*)alloc((size_t)(Gg + 1) * 4);
    (void)ws_size; (void)in_sizes; (void)n_in; (void)out_size;

    const int NB_E = (Ne + 255) / 256;       // 6250
    const int NB_N = (Nn + 255) / 256;       // 391
    const int NB_G16 = (Nn + 15) / 16;       // 6250

    hipMemsetAsync(deg, 0, (size_t)Nn * 4, stream);
    hipMemsetAsync(bnacc, 0, (size_t)Ll * 64 * 128 * 4, stream);

    k_deg<<<NB_E, 256, 0, stream>>>(dst, deg);
    k_dinv<<<NB_N, 256, 0, stream>>>(deg, dinv);
    k_scanA<<<NB_N, 256, 0, stream>>>(deg, row_off, bsum);
    k_scanB<<<1, 512, 0, stream>>>(bsum, NB_N);
    k_scanC<<<NB_N, 256, 0, stream>>>(row_off, bsum);
    k_part<<<NBLK, 256, 0, stream>>>(src, dst, tpack, idx16);
    k_csr<<<NBINS, 256, 0, stream>>>(row_off, tpack, idx16, esrc);
    k_gstart<<<1, 256, 0, stream>>>(batch, gstart);

    k_embed_gemm2<<<NGB, 256, 0, stream>>>(x, w_embed, b_embed, conv_W, h, hw);

    for (int i = 0; i < Ll; i++) {
        if (i > 0)
            k_gemmF2<<<NGB, 256, 0, stream>>>(agg, bnsc, bnsh, h,
                                              conv_W + (size_t)i * Hd * Hd, hw);
        k_gatherS<<<NB_G16, 256, 0, stream>>>(hw, dinv, row_off, esrc,
                                              conv_b + (size_t)i * Hd, agg,
                                              bnacc + (size_t)i * 64 * 128);
        k_bnfinal<<<1, 64, 0, stream>>>(bnacc + (size_t)i * 64 * 128,
                                        gamma + (size_t)i * Hd,
                                        beta + (size_t)i * Hd, bnsc, bnsh);
    }

    k_poolF<<<Gg, 1024, 0, stream>>>(agg, bnsc, bnsh, h, gstart, pooled);
    k_head<<<1, 256, 0, stream>>>(pooled, w1, b1, w2, b2, (float*)d_out);
}

// Round 7
// 501.198 us; speedup vs baseline: 2.2337x; 1.2640x over previous
//
#include <hip/hip_runtime.h>
#include <hip/hip_fp16.h>

#define Nn 100000
#define Ne 1600000
#define Fi 32
#define Hd 64
#define Ll 4
#define Gg 256
#define BN_EPS 1e-5f
#define NPB 128                      // nodes per bucket
#define NBINS ((Nn + NPB - 1) / NPB) // 782 buckets
#define CHUNK 8192                   // edges per partition block
#define NBLK ((Ne + CHUNK - 1) / CHUNK) // 196 partition blocks
#define IDXW (NBINS + 2)             // 784, u16 row stride
#define TPAD 68                      // padded LDS row stride for 64-wide tiles
#define XPAD 36                      // padded LDS row stride for 32-wide tiles
#define NGB ((Nn + 63) / 64)         // 1563 GEMM tiles

// ---------------- setup kernels ----------------

__global__ void k_deg(const int* __restrict__ dst, int* __restrict__ deg) {
    int e = blockIdx.x * blockDim.x + threadIdx.x;
    if (e < Ne) atomicAdd(&deg[dst[e]], 1);
}

__global__ void k_dinv(const int* __restrict__ deg, float* __restrict__ dinv) {
    int n = blockIdx.x * blockDim.x + threadIdx.x;
    if (n < Nn) dinv[n] = rsqrtf((float)deg[n] + 1.0f);
}

__global__ void k_scanA(const int* __restrict__ deg, int* __restrict__ row_off,
                        int* __restrict__ bsum) {
    __shared__ int s[256];
    int t = threadIdx.x;
    int i = blockIdx.x * 256 + t;
    int v = (i < Nn) ? deg[i] : 0;
    s[t] = v;
    __syncthreads();
    int x = v;
    for (int off = 1; off < 256; off <<= 1) {
        int u = (t >= off) ? s[t - off] : 0;
        __syncthreads();
        x += u;
        s[t] = x;
        __syncthreads();
    }
    if (i < Nn) row_off[i] = x - v;
    if (t == 255) bsum[blockIdx.x] = x;
}

__global__ void k_scanB(int* __restrict__ bsum, int nblk) {
    __shared__ int s[512];
    int t = threadIdx.x;
    int v = (t < nblk) ? bsum[t] : 0;
    s[t] = v;
    __syncthreads();
    int x = v;
    for (int off = 1; off < 512; off <<= 1) {
        int u = (t >= off) ? s[t - off] : 0;
        __syncthreads();
        x += u;
        s[t] = x;
        __syncthreads();
    }
    if (t < nblk) bsum[t] = x - v;
}

__global__ void k_scanC(int* __restrict__ row_off, const int* __restrict__ bsum) {
    int i = blockIdx.x * 256 + threadIdx.x;
    if (i < Nn) row_off[i] += bsum[blockIdx.x];
    if (i == 0) row_off[Nn] = Ne;
}

// block-major partition (no global atomics, coalesced writes)
__global__ __launch_bounds__(256) void k_part(const int* __restrict__ src,
                                              const int* __restrict__ dst,
                                              unsigned* __restrict__ tpack,
                                              unsigned short* __restrict__ idx16) {
    __shared__ int hist[NBINS];
    __shared__ int lofs[NBINS + 1];
    __shared__ int wsum[256];
    __shared__ unsigned stage[CHUNK];
    int blk = blockIdx.x, t = threadIdx.x;
    int e0 = blk * CHUNK;
    int nval = min(CHUNK, Ne - e0);

    for (int i = t; i < NBINS; i += 256) hist[i] = 0;
    __syncthreads();
    for (int i = t; i < nval; i += 256)
        atomicAdd(&hist[dst[e0 + i] >> 7], 1);
    __syncthreads();

    int base = t * 4;
    int loc[4];
    int s = 0;
#pragma unroll
    for (int k = 0; k < 4; k++) {
        int b = base + k;
        int c = (b < NBINS) ? hist[b] : 0;
        loc[k] = s;
        s += c;
    }
    wsum[t] = s;
    __syncthreads();
    int x = s;
    for (int off = 1; off < 256; off <<= 1) {
        int u = (t >= off) ? wsum[t - off] : 0;
        __syncthreads();
        x += u;
        wsum[t] = x;
        __syncthreads();
    }
    int excl = x - s;
#pragma unroll
    for (int k = 0; k < 4; k++) {
        int b = base + k;
        if (b < NBINS) lofs[b] = excl + loc[k];
    }
    if (t == 0) lofs[NBINS] = nval;
    __syncthreads();

    for (int i = t; i <= NBINS; i += 256)
        idx16[(size_t)blk * IDXW + i] = (unsigned short)lofs[i];

    for (int i = t; i < NBINS; i += 256) hist[i] = lofs[i];
    __syncthreads();
    for (int i = t; i < nval; i += 256) {
        int d = dst[e0 + i];
        int sv = src[e0 + i];
        int p = atomicAdd(&hist[d >> 7], 1);
        stage[p] = (unsigned)sv | ((unsigned)(d & (NPB - 1)) << 17);
    }
    __syncthreads();
    for (int i = t; i < nval; i += 256)
        tpack[(size_t)blk * CHUNK + i] = stage[i];
}

// per-bucket CSR build
__global__ __launch_bounds__(256) void k_csr(const int* __restrict__ row_off,
                                             const unsigned* __restrict__ tpack,
                                             const unsigned short* __restrict__ idx16,
                                             int* __restrict__ esrc) {
    __shared__ int rstart[NBLK], rlen[NBLK];
    __shared__ int cnt[NPB], startv[NPB];
    int b = blockIdx.x, t = threadIdx.x;
    for (int r = t; r < NBLK; r += 256) {
        const unsigned short* row = idx16 + (size_t)r * IDXW;
        int s = row[b], e = row[b + 1];
        rstart[r] = r * CHUNK + s;
        rlen[r] = e - s;
    }
    if (t < NPB) cnt[t] = 0;
    __syncthreads();
    if (t < NBLK) {
        int rs = rstart[t], rl = rlen[t];
        for (int k = 0; k < rl; k++)
            atomicAdd(&cnt[tpack[rs + k] >> 17], 1);
    }
    __syncthreads();
    if (t < NPB) startv[t] = cnt[t];
    __syncthreads();
    for (int off = 1; off < NPB; off <<= 1) {
        int x = (t < NPB && t >= off) ? startv[t - off] : 0;
        __syncthreads();
        if (t < NPB) startv[t] += x;
        __syncthreads();
    }
    if (t < NPB) cnt[t] = startv[t] - cnt[t];
    __syncthreads();
    int e0 = row_off[b * NPB];
    if (t < NBLK) {
        int rs = rstart[t], rl = rlen[t];
        for (int k = 0; k < rl; k++) {
            unsigned v = tpack[rs + k];
            int p = atomicAdd(&cnt[v >> 17], 1);
            esrc[e0 + p] = (int)(v & 0x1FFFFu);
        }
    }
}

__global__ void k_gstart(const int* __restrict__ batch, int* __restrict__ gstart) {
    int g = threadIdx.x;
    int lo = 0, hi = Nn;
    while (lo < hi) {
        int mid = (lo + hi) >> 1;
        if (batch[mid] < g) lo = mid + 1; else hi = mid;
    }
    gstart[g] = lo;
    if (g == 0) gstart[Gg] = Nn;
}

// ---------------- tiled GEMM kernels ----------------

#define MT_FMA(AV, W0, W1, W2, W3, R)                                          \
    acc[R][0] = fmaf(AV.x, W0.x, acc[R][0]);                                   \
    acc[R][0] = fmaf(AV.y, W1.x, acc[R][0]);                                   \
    acc[R][0] = fmaf(AV.z, W2.x, acc[R][0]);                                   \
    acc[R][0] = fmaf(AV.w, W3.x, acc[R][0]);                                   \
    acc[R][1] = fmaf(AV.x, W0.y, acc[R][1]);                                   \
    acc[R][1] = fmaf(AV.y, W1.y, acc[R][1]);                                   \
    acc[R][1] = fmaf(AV.z, W2.y, acc[R][1]);                                   \
    acc[R][1] = fmaf(AV.w, W3.y, acc[R][1]);                                   \
    acc[R][2] = fmaf(AV.x, W0.z, acc[R][2]);                                   \
    acc[R][2] = fmaf(AV.y, W1.z, acc[R][2]);                                   \
    acc[R][2] = fmaf(AV.z, W2.z, acc[R][2]);                                   \
    acc[R][2] = fmaf(AV.w, W3.z, acc[R][2]);                                   \
    acc[R][3] = fmaf(AV.x, W0.w, acc[R][3]);                                   \
    acc[R][3] = fmaf(AV.y, W1.w, acc[R][3]);                                   \
    acc[R][3] = fmaf(AV.z, W2.w, acc[R][3]);                                   \
    acc[R][3] = fmaf(AV.w, W3.w, acc[R][3]);

__device__ inline void store_half4(unsigned short* dst, float a, float b,
                                   float c, float d) {
    __half2 p0 = __floats2half2_rn(a, b);
    __half2 p1 = __floats2half2_rn(c, d);
    uint2 u;
    u.x = *(unsigned*)&p0;
    u.y = *(unsigned*)&p1;
    *(uint2*)dst = u;
}

// fused: hn = relu(agg*sc+sh)+h (write h), hw = hn@W (write hwh as fp16)
__global__ __launch_bounds__(256) void k_gemmF2(const float* __restrict__ agg,
                                                const float* __restrict__ bnsc,
                                                const float* __restrict__ bnsh,
                                                float* __restrict__ h,
                                                const float* __restrict__ W,
                                                unsigned short* __restrict__ hwh) {
    __shared__ float hs[64 * TPAD];
    __shared__ float ws[64 * 64];
    int t = threadIdx.x;
    int n0 = blockIdx.x * 64;

    for (int f = t; f < 1024; f += 256)
        ((float4*)ws)[f] = ((const float4*)W)[f];

    for (int f = t; f < 1024; f += 256) {
        int row = f >> 4, c4 = (f & 15) * 4;
        int node = n0 + row;
        if (node < Nn) {
            float4 a  = *(const float4*)(agg + (size_t)node * Hd + c4);
            float4 ho = *(const float4*)(h + (size_t)node * Hd + c4);
            float4 sc = ((const float4*)bnsc)[f & 15];
            float4 sh = ((const float4*)bnsh)[f & 15];
            float4 r4;
            r4.x = fmaxf(fmaf(a.x, sc.x, sh.x), 0.f) + ho.x;
            r4.y = fmaxf(fmaf(a.y, sc.y, sh.y), 0.f) + ho.y;
            r4.z = fmaxf(fmaf(a.z, sc.z, sh.z), 0.f) + ho.z;
            r4.w = fmaxf(fmaf(a.w, sc.w, sh.w), 0.f) + ho.w;
            *(float4*)(h + (size_t)node * Hd + c4) = r4;
            *(float4*)&hs[row * TPAD + c4] = r4;
        } else {
            *(float4*)&hs[row * TPAD + c4] = make_float4(0.f, 0.f, 0.f, 0.f);
        }
    }
    __syncthreads();

    int i = t >> 4, j = t & 15;
    float acc[4][4] = {};
#pragma unroll
    for (int k = 0; k < 64; k += 4) {
        float4 w0 = *(const float4*)&ws[(k + 0) * 64 + 4 * j];
        float4 w1 = *(const float4*)&ws[(k + 1) * 64 + 4 * j];
        float4 w2 = *(const float4*)&ws[(k + 2) * 64 + 4 * j];
        float4 w3 = *(const float4*)&ws[(k + 3) * 64 + 4 * j];
        float4 a0 = *(const float4*)&hs[(4 * i + 0) * TPAD + k];
        float4 a1 = *(const float4*)&hs[(4 * i + 1) * TPAD + k];
        float4 a2 = *(const float4*)&hs[(4 * i + 2) * TPAD + k];
        float4 a3 = *(const float4*)&hs[(4 * i + 3) * TPAD + k];
        MT_FMA(a0, w0, w1, w2, w3, 0)
        MT_FMA(a1, w0, w1, w2, w3, 1)
        MT_FMA(a2, w0, w1, w2, w3, 2)
        MT_FMA(a3, w0, w1, w2, w3, 3)
    }
#pragma unroll
    for (int r = 0; r < 4; r++) {
        int node = n0 + 4 * i + r;
        if (node < Nn)
            store_half4(hwh + (size_t)node * Hd + 4 * j,
                        acc[r][0], acc[r][1], acc[r][2], acc[r][3]);
    }
}

// fused: h = x@we+be (write h), hw = h@W0 (write hwh as fp16)
__global__ __launch_bounds__(256) void k_embed_gemm2(const float* __restrict__ x,
                                                     const float* __restrict__ we,
                                                     const float* __restrict__ be,
                                                     const float* __restrict__ W,
                                                     float* __restrict__ h,
                                                     unsigned short* __restrict__ hwh) {
    __shared__ float xs[64 * XPAD];
    __shared__ float wes[32 * 64];
    __shared__ float hs[64 * TPAD];
    __shared__ float ws[64 * 64];
    __shared__ float bes[64];
    int t = threadIdx.x;
    int n0 = blockIdx.x * 64;

    for (int f = t; f < 512; f += 256)
        ((float4*)wes)[f] = ((const float4*)we)[f];
    for (int f = t; f < 1024; f += 256)
        ((float4*)ws)[f] = ((const float4*)W)[f];
    if (t < 64) bes[t] = be[t];

    for (int f = t; f < 512; f += 256) {
        int row = f >> 3, c4 = (f & 7) * 4;
        int node = n0 + row;
        float4 v = (node < Nn) ? *(const float4*)(x + (size_t)node * Fi + c4)
                               : make_float4(0.f, 0.f, 0.f, 0.f);
        *(float4*)&xs[row * XPAD + c4] = v;
    }
    __syncthreads();

    int i = t >> 4, j = t & 15;
    {
        float acc[4][4];
#pragma unroll
        for (int r = 0; r < 4; r++)
#pragma unroll
            for (int c = 0; c < 4; c++) acc[r][c] = bes[4 * j + c];
#pragma unroll
        for (int k = 0; k < 32; k += 4) {
            float4 w0 = *(const float4*)&wes[(k + 0) * 64 + 4 * j];
            float4 w1 = *(const float4*)&wes[(k + 1) * 64 + 4 * j];
            float4 w2 = *(const float4*)&wes[(k + 2) * 64 + 4 * j];
            float4 w3 = *(const float4*)&wes[(k + 3) * 64 + 4 * j];
            float4 a0 = *(const float4*)&xs[(4 * i + 0) * XPAD + k];
            float4 a1 = *(const float4*)&xs[(4 * i + 1) * XPAD + k];
            float4 a2 = *(const float4*)&xs[(4 * i + 2) * XPAD + k];
            float4 a3 = *(const float4*)&xs[(4 * i + 3) * XPAD + k];
            MT_FMA(a0, w0, w1, w2, w3, 0)
            MT_FMA(a1, w0, w1, w2, w3, 1)
            MT_FMA(a2, w0, w1, w2, w3, 2)
            MT_FMA(a3, w0, w1, w2, w3, 3)
        }
#pragma unroll
        for (int r = 0; r < 4; r++) {
            int node = n0 + 4 * i + r;
            float4 hv = make_float4(acc[r][0], acc[r][1], acc[r][2], acc[r][3]);
            *(float4*)&hs[(4 * i + r) * TPAD + 4 * j] = hv;
            if (node < Nn)
                *(float4*)(h + (size_t)node * Hd + 4 * j) = hv;
        }
    }
    __syncthreads();
    {
        float acc[4][4] = {};
#pragma unroll
        for (int k = 0; k < 64; k += 4) {
            float4 w0 = *(const float4*)&ws[(k + 0) * 64 + 4 * j];
            float4 w1 = *(const float4*)&ws[(k + 1) * 64 + 4 * j];
            float4 w2 = *(const float4*)&ws[(k + 2) * 64 + 4 * j];
            float4 w3 = *(const float4*)&ws[(k + 3) * 64 + 4 * j];
            float4 a0 = *(const float4*)&hs[(4 * i + 0) * TPAD + k];
            float4 a1 = *(const float4*)&hs[(4 * i + 1) * TPAD + k];
            float4 a2 = *(const float4*)&hs[(4 * i + 2) * TPAD + k];
            float4 a3 = *(const float4*)&hs[(4 * i + 3) * TPAD + k];
            MT_FMA(a0, w0, w1, w2, w3, 0)
            MT_FMA(a1, w0, w1, w2, w3, 1)
            MT_FMA(a2, w0, w1, w2, w3, 2)
            MT_FMA(a3, w0, w1, w2, w3, 3)
        }
#pragma unroll
        for (int r = 0; r < 4; r++) {
            int node = n0 + 4 * i + r;
            if (node < Nn)
                store_half4(hwh + (size_t)node * Hd + 4 * j,
                            acc[r][0], acc[r][1], acc[r][2], acc[r][3]);
        }
    }
}

// ---------------- gather / bn / pool / head ----------------

// fp16 gather: 8 lanes per node, 8 channels per lane (uint4 = 8 halves)
__global__ __launch_bounds__(256) void k_gatherH(const unsigned short* __restrict__ hwh,
                                                 const float* __restrict__ dinv,
                                                 const int* __restrict__ row_off,
                                                 const int* __restrict__ esrc,
                                                 const float* __restrict__ bias,
                                                 float* __restrict__ agg,
                                                 float* __restrict__ bnacc) {
    int g = threadIdx.x >> 3;   // 32 node slots
    int l = threadIdx.x & 7;    // lane in node group
    int node = blockIdx.x * 32 + g;   // Nn % 32 == 0
    float di = dinv[node];
    float scl = di * di;
    float acc[8];

    uint4 v = *(const uint4*)(hwh + (size_t)node * Hd + l * 8);
#pragma unroll
    for (int q = 0; q < 4; q++) {
        __half2 hp = *(__half2*)(((unsigned*)&v) + q);
        float2 f = __half22float2(hp);
        acc[2 * q]     = f.x * scl + bias[l * 8 + 2 * q];
        acc[2 * q + 1] = f.y * scl + bias[l * 8 + 2 * q + 1];
    }

    int e = row_off[node], e1 = row_off[node + 1];
    for (; e + 3 < e1; e += 4) {
        int s0 = esrc[e], s1 = esrc[e + 1], s2 = esrc[e + 2], s3 = esrc[e + 3];
        float c0 = dinv[s0] * di, c1 = dinv[s1] * di;
        float c2 = dinv[s2] * di, c3 = dinv[s3] * di;
        uint4 v0 = *(const uint4*)(hwh + (size_t)s0 * Hd + l * 8);
        uint4 v1 = *(const uint4*)(hwh + (size_t)s1 * Hd + l * 8);
        uint4 v2 = *(const uint4*)(hwh + (size_t)s2 * Hd + l * 8);
        uint4 v3 = *(const uint4*)(hwh + (size_t)s3 * Hd + l * 8);
#pragma unroll
        for (int q = 0; q < 4; q++) {
            float2 f0 = __half22float2(*(__half2*)(((unsigned*)&v0) + q));
            float2 f1 = __half22float2(*(__half2*)(((unsigned*)&v1) + q));
            float2 f2 = __half22float2(*(__half2*)(((unsigned*)&v2) + q));
            float2 f3 = __half22float2(*(__half2*)(((unsigned*)&v3) + q));
            acc[2 * q]     = fmaf(f0.x, c0, acc[2 * q]);
            acc[2 * q + 1] = fmaf(f0.y, c0, acc[2 * q + 1]);
            acc[2 * q]     = fmaf(f1.x, c1, acc[2 * q]);
            acc[2 * q + 1] = fmaf(f1.y, c1, acc[2 * q + 1]);
            acc[2 * q]     = fmaf(f2.x, c2, acc[2 * q]);
            acc[2 * q + 1] = fmaf(f2.y, c2, acc[2 * q + 1]);
            acc[2 * q]     = fmaf(f3.x, c3, acc[2 * q]);
            acc[2 * q + 1] = fmaf(f3.y, c3, acc[2 * q + 1]);
        }
    }
    for (; e < e1; e++) {
        int s0 = esrc[e];
        float c0 = dinv[s0] * di;
        uint4 v0 = *(const uint4*)(hwh + (size_t)s0 * Hd + l * 8);
#pragma unroll
        for (int q = 0; q < 4; q++) {
            float2 f0 = __half22float2(*(__half2*)(((unsigned*)&v0) + q));
            acc[2 * q]     = fmaf(f0.x, c0, acc[2 * q]);
            acc[2 * q + 1] = fmaf(f0.y, c0, acc[2 * q + 1]);
        }
    }

    *(float4*)(agg + (size_t)node * Hd + l * 8)     = make_float4(acc[0], acc[1], acc[2], acc[3]);
    *(float4*)(agg + (size_t)node * Hd + l * 8 + 4) = make_float4(acc[4], acc[5], acc[6], acc[7]);

    // bn stats: block reduce over 32 node slots, sharded atomics
    __shared__ float ls[2048];
    *(float4*)&ls[g * 64 + l * 8]     = make_float4(acc[0], acc[1], acc[2], acc[3]);
    *(float4*)&ls[g * 64 + l * 8 + 4] = make_float4(acc[4], acc[5], acc[6], acc[7]);
    __syncthreads();
    int t = threadIdx.x;
    if (t < 64) {
        float s = 0.f, s2 = 0.f;
#pragma unroll
        for (int gg = 0; gg < 32; gg++) {
            float vv = ls[gg * 64 + t];
            s += vv;
            s2 = fmaf(vv, vv, s2);
        }
        float* a = bnacc + (blockIdx.x & 63) * 128;
        atomicAdd(&a[t], s);
        atomicAdd(&a[64 + t], s2);
    }
}

__global__ void k_bnfinal(const float* __restrict__ acc, const float* __restrict__ gamma,
                          const float* __restrict__ beta, float* __restrict__ bnsc,
                          float* __restrict__ bnsh) {
    int c = threadIdx.x;
    if (c >= 64) return;
    float s = 0.f, s2 = 0.f;
    for (int sh = 0; sh < 64; sh++) {
        s  += acc[sh * 128 + c];
        s2 += acc[sh * 128 + 64 + c];
    }
    float mean = s / (float)Nn;
    float var = s2 / (float)Nn - mean * mean;
    var = fmaxf(var, 0.f);
    float sc = gamma[c] * rsqrtf(var + BN_EPS);
    bnsc[c] = sc;
    bnsh[c] = beta[c] - mean * sc;
}

__global__ __launch_bounds__(1024) void k_poolF(const float* __restrict__ agg,
                                                const float* __restrict__ bnsc,
                                                const float* __restrict__ bnsh,
                                                const float* __restrict__ h,
                                                const int* __restrict__ gstart,
                                                float* __restrict__ pooled) {
    int g = blockIdx.x;
    int t = threadIdx.x;
    int ch = t & 63, sl = t >> 6;
    float sc = bnsc[ch], shv = bnsh[ch];
    int n0 = gstart[g], n1 = gstart[g + 1];
    float s = 0.f;
    for (int n = n0 + sl; n < n1; n += 16) {
        float a  = agg[(size_t)n * Hd + ch];
        float ho = h[(size_t)n * Hd + ch];
        s += fmaxf(fmaf(a, sc, shv), 0.f) + ho;
    }
    __shared__ float ls[1024];
    ls[t] = s;
    __syncthreads();
    if (t < 64) {
        float acc = 0.f;
#pragma unroll
        for (int k = 0; k < 16; k++) acc += ls[k * 64 + t];
        float cnt = (float)(n1 - n0);
        pooled[g * Hd + t] = acc / fmaxf(cnt, 1.0f);
    }
}

__global__ __launch_bounds__(256) void k_head(const float* __restrict__ pooled,
                                              const float* __restrict__ w1,
                                              const float* __restrict__ b1,
                                              const float* __restrict__ w2,
                                              const float* __restrict__ b2,
                                              float* __restrict__ out) {
    __shared__ float sw1[Hd * 32], sw2[32], sb1[32];
    int t = threadIdx.x;
    for (int i = t; i < Hd * 32; i += 256) sw1[i] = w1[i];
    if (t < 32) { sw2[t] = w2[t]; sb1[t] = b1[t]; }
    __syncthreads();
    float acc2[32];
#pragma unroll
    for (int k = 0; k < 32; k++) acc2[k] = sb1[k];
    for (int j = 0; j < Hd; j++) {
        float pj = pooled[t * Hd + j];
#pragma unroll
        for (int k = 0; k < 32; k++) acc2[k] = fmaf(pj, sw1[j * 32 + k], acc2[k]);
    }
    float o = b2[0];
#pragma unroll
    for (int k = 0; k < 32; k++) o += fmaxf(acc2[k], 0.f) * sw2[k];
    out[t] = o;
}

// ---------------- launch ----------------

extern "C" void kernel_launch(void* const* d_in, const int* in_sizes, int n_in,
                              void* d_out, int out_size, void* d_ws, size_t ws_size,
                              hipStream_t stream) {
    const float* x       = (const float*)d_in[0];
    const int*   eidx    = (const int*)d_in[1];
    const int*   batch   = (const int*)d_in[2];
    const float* w_embed = (const float*)d_in[3];
    const float* b_embed = (const float*)d_in[4];
    const float* conv_W  = (const float*)d_in[5];
    const float* conv_b  = (const float*)d_in[6];
    const float* gamma   = (const float*)d_in[7];
    const float* beta    = (const float*)d_in[8];
    const float* w1      = (const float*)d_in[9];
    const float* b1      = (const float*)d_in[10];
    const float* w2      = (const float*)d_in[11];
    const float* b2      = (const float*)d_in[12];
    const int* src = eidx;
    const int* dst = eidx + Ne;

    char* p = (char*)d_ws;
    auto alloc = [&](size_t bytes) -> void* {
        void* r = (void*)p;
        p += (bytes + 255) / 256 * 256;
        return r;
    };
    float*    h       = (float*)alloc((size_t)Nn * Hd * 4);
    unsigned short* hwh = (unsigned short*)alloc((size_t)Nn * Hd * 2);
    float*    agg     = (float*)alloc((size_t)Nn * Hd * 4);
    int*      deg     = (int*)alloc((size_t)Nn * 4);
    int*      row_off = (int*)alloc((size_t)(Nn + 1) * 4);
    float*    dinv    = (float*)alloc((size_t)Nn * 4);
    int*      bsum    = (int*)alloc(512 * 4);
    int*      esrc    = (int*)alloc((size_t)Ne * 4);
    unsigned* tpack   = (unsigned*)alloc((size_t)NBLK * CHUNK * 4);
    unsigned short* idx16 = (unsigned short*)alloc((size_t)NBLK * IDXW * 2);
    float*    bnacc   = (float*)alloc((size_t)Ll * 64 * 128 * 4);
    float*    bnsc    = (float*)alloc(64 * 4);
    float*    bnsh    = (float*)alloc(64 * 4);
    float*    pooled  = (float*)alloc((size_t)Gg * Hd * 4);
    int*      gstart  = (int*)alloc((size_t)(Gg + 1) * 4);
    (void)ws_size; (void)in_sizes; (void)n_in; (void)out_size;

    const int NB_E = (Ne + 255) / 256;       // 6250
    const int NB_N = (Nn + 255) / 256;       // 391
    const int NB_G32 = (Nn + 31) / 32;       // 3125

    hipMemsetAsync(deg, 0, (size_t)Nn * 4, stream);
    hipMemsetAsync(bnacc, 0, (size_t)Ll * 64 * 128 * 4, stream);

    k_deg<<<NB_E, 256, 0, stream>>>(dst, deg);
    k_dinv<<<NB_N, 256, 0, stream>>>(deg, dinv);
    k_scanA<<<NB_N, 256, 0, stream>>>(deg, row_off, bsum);
    k_scanB<<<1, 512, 0, stream>>>(bsum, NB_N);
    k_scanC<<<NB_N, 256, 0, stream>>>(row_off, bsum);
    k_part<<<NBLK, 256, 0, stream>>>(src, dst, tpack, idx16);
    k_csr<<<NBINS, 256, 0, stream>>>(row_off, tpack, idx16, esrc);
    k_gstart<<<1, 256, 0, stream>>>(batch, gstart);

    k_embed_gemm2<<<NGB, 256, 0, stream>>>(x, w_embed, b_embed, conv_W, h, hwh);

    for (int i = 0; i < Ll; i++) {
        if (i > 0)
            k_gemmF2<<<NGB, 256, 0, stream>>>(agg, bnsc, bnsh, h,
                                              conv_W + (size_t)i * Hd * Hd, hwh);
        k_gatherH<<<NB_G32, 256, 0, stream>>>(hwh, dinv, row_off, esrc,
                                              conv_b + (size_t)i * Hd, agg,
                                              bnacc + (size_t)i * 64 * 128);
        k_bnfinal<<<1, 64, 0, stream>>>(bnacc + (size_t)i * 64 * 128,
                                        gamma + (size_t)i * Hd,
                                        beta + (size_t)i * Hd, bnsc, bnsh);
    }

    k_poolF<<<Gg, 1024, 0, stream>>>(agg, bnsc, bnsh, h, gstart, pooled);
    k_head<<<1, 256, 0, stream>>>(pooled, w1, b1, w2, b2, (float*)d_out);
}

// Round 8
// 448.625 us; speedup vs baseline: 2.4954x; 1.1172x over previous
//
#include <hip/hip_runtime.h>
#include <hip/hip_fp16.h>

#define Nn 100000
#define Ne 1600000
#define Fi 32
#define Hd 64
#define Ll 4
#define Gg 256
#define BN_EPS 1e-5f
#define NPB 128                      // nodes per bucket
#define NBINS ((Nn + NPB - 1) / NPB) // 782 buckets
#define CHUNK 8192                   // edges per partition block
#define NBLK ((Ne + CHUNK - 1) / CHUNK) // 196 partition blocks
#define IDXW (NBINS + 2)             // 784, u16 row stride
#define TPAD 68                      // padded LDS row stride for 64-wide tiles
#define XPAD 36                      // padded LDS row stride for 32-wide tiles
#define NGB ((Nn + 63) / 64)         // 1563 GEMM tiles

// ---------------- setup kernels ----------------

__global__ void k_dinv(const int* __restrict__ deg, float* __restrict__ dinv) {
    int n = blockIdx.x * blockDim.x + threadIdx.x;
    if (n < Nn) dinv[n] = rsqrtf((float)deg[n] + 1.0f);
}

__global__ void k_scanA(const int* __restrict__ deg, int* __restrict__ row_off,
                        int* __restrict__ bsum) {
    __shared__ int s[256];
    int t = threadIdx.x;
    int i = blockIdx.x * 256 + t;
    int v = (i < Nn) ? deg[i] : 0;
    s[t] = v;
    __syncthreads();
    int x = v;
    for (int off = 1; off < 256; off <<= 1) {
        int u = (t >= off) ? s[t - off] : 0;
        __syncthreads();
        x += u;
        s[t] = x;
        __syncthreads();
    }
    if (i < Nn) row_off[i] = x - v;
    if (t == 255) bsum[blockIdx.x] = x;
}

__global__ void k_scanB(int* __restrict__ bsum, int nblk) {
    __shared__ int s[512];
    int t = threadIdx.x;
    int v = (t < nblk) ? bsum[t] : 0;
    s[t] = v;
    __syncthreads();
    int x = v;
    for (int off = 1; off < 512; off <<= 1) {
        int u = (t >= off) ? s[t - off] : 0;
        __syncthreads();
        x += u;
        s[t] = x;
        __syncthreads();
    }
    if (t < nblk) bsum[t] = x - v;
}

__global__ void k_scanC(int* __restrict__ row_off, const int* __restrict__ bsum) {
    int i = blockIdx.x * 256 + threadIdx.x;
    if (i < Nn) row_off[i] += bsum[blockIdx.x];
    if (i == 0) row_off[Nn] = Ne;
}

// block-major partition (no global atomics, coalesced writes)
__global__ __launch_bounds__(256) void k_part(const int* __restrict__ src,
                                              const int* __restrict__ dst,
                                              unsigned* __restrict__ tpack,
                                              unsigned short* __restrict__ idx16) {
    __shared__ int hist[NBINS];
    __shared__ int lofs[NBINS + 1];
    __shared__ int wsum[256];
    __shared__ unsigned stage[CHUNK];
    int blk = blockIdx.x, t = threadIdx.x;
    int e0 = blk * CHUNK;
    int nval = min(CHUNK, Ne - e0);

    for (int i = t; i < NBINS; i += 256) hist[i] = 0;
    __syncthreads();
    for (int i = t; i < nval; i += 256)
        atomicAdd(&hist[dst[e0 + i] >> 7], 1);
    __syncthreads();

    int base = t * 4;
    int loc[4];
    int s = 0;
#pragma unroll
    for (int k = 0; k < 4; k++) {
        int b = base + k;
        int c = (b < NBINS) ? hist[b] : 0;
        loc[k] = s;
        s += c;
    }
    wsum[t] = s;
    __syncthreads();
    int x = s;
    for (int off = 1; off < 256; off <<= 1) {
        int u = (t >= off) ? wsum[t - off] : 0;
        __syncthreads();
        x += u;
        wsum[t] = x;
        __syncthreads();
    }
    int excl = x - s;
#pragma unroll
    for (int k = 0; k < 4; k++) {
        int b = base + k;
        if (b < NBINS) lofs[b] = excl + loc[k];
    }
    if (t == 0) lofs[NBINS] = nval;
    __syncthreads();

    for (int i = t; i <= NBINS; i += 256)
        idx16[(size_t)blk * IDXW + i] = (unsigned short)lofs[i];

    for (int i = t; i < NBINS; i += 256) hist[i] = lofs[i];
    __syncthreads();
    for (int i = t; i < nval; i += 256) {
        int d = dst[e0 + i];
        int sv = src[e0 + i];
        int p = atomicAdd(&hist[d >> 7], 1);
        stage[p] = (unsigned)sv | ((unsigned)(d & (NPB - 1)) << 17);
    }
    __syncthreads();
    for (int i = t; i < nval; i += 256)
        tpack[(size_t)blk * CHUNK + i] = stage[i];
}

// degree from partitioned tpack: one block per bucket, LDS histogram,
// coalesced deg writes, zero global atomics
__global__ __launch_bounds__(256) void k_deg2(const unsigned* __restrict__ tpack,
                                              const unsigned short* __restrict__ idx16,
                                              int* __restrict__ deg) {
    __shared__ int cnt[NPB];
    int b = blockIdx.x, t = threadIdx.x;
    if (t < NPB) cnt[t] = 0;
    __syncthreads();
    if (t < NBLK) {
        const unsigned short* row = idx16 + (size_t)t * IDXW;
        int s = row[b], e = row[b + 1];
        const unsigned* tp = tpack + (size_t)t * CHUNK;
        for (int k = s; k < e; k++)
            atomicAdd(&cnt[tp[k] >> 17], 1);
    }
    __syncthreads();
    int node = b * NPB + t;
    if (t < NPB && node < Nn) deg[node] = cnt[t];
}

// per-bucket CSR scatter; cursors come straight from row_off (no histogram)
__global__ __launch_bounds__(256) void k_csr(const int* __restrict__ row_off,
                                             const unsigned* __restrict__ tpack,
                                             const unsigned short* __restrict__ idx16,
                                             int* __restrict__ esrc) {
    __shared__ int cur[NPB];
    int b = blockIdx.x, t = threadIdx.x;
    int n0 = b * NPB;
    int e0 = row_off[n0];
    if (t < NPB) {
        int node = n0 + t;
        cur[t] = (node < Nn) ? (row_off[node] - e0) : 0;
    }
    __syncthreads();
    if (t < NBLK) {
        const unsigned short* row = idx16 + (size_t)t * IDXW;
        int s = row[b], e = row[b + 1];
        const unsigned* tp = tpack + (size_t)t * CHUNK;
        for (int k = s; k < e; k++) {
            unsigned v = tp[k];
            int p = atomicAdd(&cur[v >> 17], 1);
            esrc[e0 + p] = (int)(v & 0x1FFFFu);
        }
    }
}

__global__ void k_gstart(const int* __restrict__ batch, int* __restrict__ gstart) {
    int g = threadIdx.x;
    int lo = 0, hi = Nn;
    while (lo < hi) {
        int mid = (lo + hi) >> 1;
        if (batch[mid] < g) lo = mid + 1; else hi = mid;
    }
    gstart[g] = lo;
    if (g == 0) gstart[Gg] = Nn;
}

// ---------------- tiled GEMM kernels ----------------

#define MT_FMA(AV, W0, W1, W2, W3, R)                                          \
    acc[R][0] = fmaf(AV.x, W0.x, acc[R][0]);                                   \
    acc[R][0] = fmaf(AV.y, W1.x, acc[R][0]);                                   \
    acc[R][0] = fmaf(AV.z, W2.x, acc[R][0]);                                   \
    acc[R][0] = fmaf(AV.w, W3.x, acc[R][0]);                                   \
    acc[R][1] = fmaf(AV.x, W0.y, acc[R][1]);                                   \
    acc[R][1] = fmaf(AV.y, W1.y, acc[R][1]);                                   \
    acc[R][1] = fmaf(AV.z, W2.y, acc[R][1]);                                   \
    acc[R][1] = fmaf(AV.w, W3.y, acc[R][1]);                                   \
    acc[R][2] = fmaf(AV.x, W0.z, acc[R][2]);                                   \
    acc[R][2] = fmaf(AV.y, W1.z, acc[R][2]);                                   \
    acc[R][2] = fmaf(AV.z, W2.z, acc[R][2]);                                   \
    acc[R][2] = fmaf(AV.w, W3.z, acc[R][2]);                                   \
    acc[R][3] = fmaf(AV.x, W0.w, acc[R][3]);                                   \
    acc[R][3] = fmaf(AV.y, W1.w, acc[R][3]);                                   \
    acc[R][3] = fmaf(AV.z, W2.w, acc[R][3]);                                   \
    acc[R][3] = fmaf(AV.w, W3.w, acc[R][3]);

__device__ inline void store_half4(unsigned short* dst, float a, float b,
                                   float c, float d) {
    __half2 p0 = __floats2half2_rn(a, b);
    __half2 p1 = __floats2half2_rn(c, d);
    uint2 u;
    u.x = *(unsigned*)&p0;
    u.y = *(unsigned*)&p1;
    *(uint2*)dst = u;
}

// fused: hn = relu(agg*sc+sh)+h (write h), hw = hn@W (write hwh as fp16)
__global__ __launch_bounds__(256) void k_gemmF2(const float* __restrict__ agg,
                                                const float* __restrict__ bnsc,
                                                const float* __restrict__ bnsh,
                                                float* __restrict__ h,
                                                const float* __restrict__ W,
                                                unsigned short* __restrict__ hwh) {
    __shared__ float hs[64 * TPAD];
    __shared__ float ws[64 * 64];
    int t = threadIdx.x;
    int n0 = blockIdx.x * 64;

    for (int f = t; f < 1024; f += 256)
        ((float4*)ws)[f] = ((const float4*)W)[f];

    for (int f = t; f < 1024; f += 256) {
        int row = f >> 4, c4 = (f & 15) * 4;
        int node = n0 + row;
        if (node < Nn) {
            float4 a  = *(const float4*)(agg + (size_t)node * Hd + c4);
            float4 ho = *(const float4*)(h + (size_t)node * Hd + c4);
            float4 sc = ((const float4*)bnsc)[f & 15];
            float4 sh = ((const float4*)bnsh)[f & 15];
            float4 r4;
            r4.x = fmaxf(fmaf(a.x, sc.x, sh.x), 0.f) + ho.x;
            r4.y = fmaxf(fmaf(a.y, sc.y, sh.y), 0.f) + ho.y;
            r4.z = fmaxf(fmaf(a.z, sc.z, sh.z), 0.f) + ho.z;
            r4.w = fmaxf(fmaf(a.w, sc.w, sh.w), 0.f) + ho.w;
            *(float4*)(h + (size_t)node * Hd + c4) = r4;
            *(float4*)&hs[row * TPAD + c4] = r4;
        } else {
            *(float4*)&hs[row * TPAD + c4] = make_float4(0.f, 0.f, 0.f, 0.f);
        }
    }
    __syncthreads();

    int i = t >> 4, j = t & 15;
    float acc[4][4] = {};
#pragma unroll
    for (int k = 0; k < 64; k += 4) {
        float4 w0 = *(const float4*)&ws[(k + 0) * 64 + 4 * j];
        float4 w1 = *(const float4*)&ws[(k + 1) * 64 + 4 * j];
        float4 w2 = *(const float4*)&ws[(k + 2) * 64 + 4 * j];
        float4 w3 = *(const float4*)&ws[(k + 3) * 64 + 4 * j];
        float4 a0 = *(const float4*)&hs[(4 * i + 0) * TPAD + k];
        float4 a1 = *(const float4*)&hs[(4 * i + 1) * TPAD + k];
        float4 a2 = *(const float4*)&hs[(4 * i + 2) * TPAD + k];
        float4 a3 = *(const float4*)&hs[(4 * i + 3) * TPAD + k];
        MT_FMA(a0, w0, w1, w2, w3, 0)
        MT_FMA(a1, w0, w1, w2, w3, 1)
        MT_FMA(a2, w0, w1, w2, w3, 2)
        MT_FMA(a3, w0, w1, w2, w3, 3)
    }
#pragma unroll
    for (int r = 0; r < 4; r++) {
        int node = n0 + 4 * i + r;
        if (node < Nn)
            store_half4(hwh + (size_t)node * Hd + 4 * j,
                        acc[r][0], acc[r][1], acc[r][2], acc[r][3]);
    }
}

// fused: h = x@we+be (write h), hw = h@W0 (write hwh as fp16)
__global__ __launch_bounds__(256) void k_embed_gemm2(const float* __restrict__ x,
                                                     const float* __restrict__ we,
                                                     const float* __restrict__ be,
                                                     const float* __restrict__ W,
                                                     float* __restrict__ h,
                                                     unsigned short* __restrict__ hwh) {
    __shared__ float xs[64 * XPAD];
    __shared__ float wes[32 * 64];
    __shared__ float hs[64 * TPAD];
    __shared__ float ws[64 * 64];
    __shared__ float bes[64];
    int t = threadIdx.x;
    int n0 = blockIdx.x * 64;

    for (int f = t; f < 512; f += 256)
        ((float4*)wes)[f] = ((const float4*)we)[f];
    for (int f = t; f < 1024; f += 256)
        ((float4*)ws)[f] = ((const float4*)W)[f];
    if (t < 64) bes[t] = be[t];

    for (int f = t; f < 512; f += 256) {
        int row = f >> 3, c4 = (f & 7) * 4;
        int node = n0 + row;
        float4 v = (node < Nn) ? *(const float4*)(x + (size_t)node * Fi + c4)
                               : make_float4(0.f, 0.f, 0.f, 0.f);
        *(float4*)&xs[row * XPAD + c4] = v;
    }
    __syncthreads();

    int i = t >> 4, j = t & 15;
    {
        float acc[4][4];
#pragma unroll
        for (int r = 0; r < 4; r++)
#pragma unroll
            for (int c = 0; c < 4; c++) acc[r][c] = bes[4 * j + c];
#pragma unroll
        for (int k = 0; k < 32; k += 4) {
            float4 w0 = *(const float4*)&wes[(k + 0) * 64 + 4 * j];
            float4 w1 = *(const float4*)&wes[(k + 1) * 64 + 4 * j];
            float4 w2 = *(const float4*)&wes[(k + 2) * 64 + 4 * j];
            float4 w3 = *(const float4*)&wes[(k + 3) * 64 + 4 * j];
            float4 a0 = *(const float4*)&xs[(4 * i + 0) * XPAD + k];
            float4 a1 = *(const float4*)&xs[(4 * i + 1) * XPAD + k];
            float4 a2 = *(const float4*)&xs[(4 * i + 2) * XPAD + k];
            float4 a3 = *(const float4*)&xs[(4 * i + 3) * XPAD + k];
            MT_FMA(a0, w0, w1, w2, w3, 0)
            MT_FMA(a1, w0, w1, w2, w3, 1)
            MT_FMA(a2, w0, w1, w2, w3, 2)
            MT_FMA(a3, w0, w1, w2, w3, 3)
        }
#pragma unroll
        for (int r = 0; r < 4; r++) {
            int node = n0 + 4 * i + r;
            float4 hv = make_float4(acc[r][0], acc[r][1], acc[r][2], acc[r][3]);
            *(float4*)&hs[(4 * i + r) * TPAD + 4 * j] = hv;
            if (node < Nn)
                *(float4*)(h + (size_t)node * Hd + 4 * j) = hv;
        }
    }
    __syncthreads();
    {
        float acc[4][4] = {};
#pragma unroll
        for (int k = 0; k < 64; k += 4) {
            float4 w0 = *(const float4*)&ws[(k + 0) * 64 + 4 * j];
            float4 w1 = *(const float4*)&ws[(k + 1) * 64 + 4 * j];
            float4 w2 = *(const float4*)&ws[(k + 2) * 64 + 4 * j];
            float4 w3 = *(const float4*)&ws[(k + 3) * 64 + 4 * j];
            float4 a0 = *(const float4*)&hs[(4 * i + 0) * TPAD + k];
            float4 a1 = *(const float4*)&hs[(4 * i + 1) * TPAD + k];
            float4 a2 = *(const float4*)&hs[(4 * i + 2) * TPAD + k];
            float4 a3 = *(const float4*)&hs[(4 * i + 3) * TPAD + k];
            MT_FMA(a0, w0, w1, w2, w3, 0)
            MT_FMA(a1, w0, w1, w2, w3, 1)
            MT_FMA(a2, w0, w1, w2, w3, 2)
            MT_FMA(a3, w0, w1, w2, w3, 3)
        }
#pragma unroll
        for (int r = 0; r < 4; r++) {
            int node = n0 + 4 * i + r;
            if (node < Nn)
                store_half4(hwh + (size_t)node * Hd + 4 * j,
                            acc[r][0], acc[r][1], acc[r][2], acc[r][3]);
        }
    }
}

// ---------------- gather / bn / pool / head ----------------

// fp16 gather: 8 lanes per node, 8 channels per lane (uint4 = 8 halves)
__global__ __launch_bounds__(256) void k_gatherH(const unsigned short* __restrict__ hwh,
                                                 const float* __restrict__ dinv,
                                                 const int* __restrict__ row_off,
                                                 const int* __restrict__ esrc,
                                                 const float* __restrict__ bias,
                                                 float* __restrict__ agg,
                                                 float* __restrict__ bnacc) {
    int g = threadIdx.x >> 3;   // 32 node slots
    int l = threadIdx.x & 7;    // lane in node group
    int node = blockIdx.x * 32 + g;   // Nn % 32 == 0
    float di = dinv[node];
    float scl = di * di;
    float acc[8];

    uint4 v = *(const uint4*)(hwh + (size_t)node * Hd + l * 8);
#pragma unroll
    for (int q = 0; q < 4; q++) {
        __half2 hp = *(__half2*)(((unsigned*)&v) + q);
        float2 f = __half22float2(hp);
        acc[2 * q]     = f.x * scl + bias[l * 8 + 2 * q];
        acc[2 * q + 1] = f.y * scl + bias[l * 8 + 2 * q + 1];
    }

    int e = row_off[node], e1 = row_off[node + 1];
    for (; e + 3 < e1; e += 4) {
        int s0 = esrc[e], s1 = esrc[e + 1], s2 = esrc[e + 2], s3 = esrc[e + 3];
        float c0 = dinv[s0] * di, c1 = dinv[s1] * di;
        float c2 = dinv[s2] * di, c3 = dinv[s3] * di;
        uint4 v0 = *(const uint4*)(hwh + (size_t)s0 * Hd + l * 8);
        uint4 v1 = *(const uint4*)(hwh + (size_t)s1 * Hd + l * 8);
        uint4 v2 = *(const uint4*)(hwh + (size_t)s2 * Hd + l * 8);
        uint4 v3 = *(const uint4*)(hwh + (size_t)s3 * Hd + l * 8);
#pragma unroll
        for (int q = 0; q < 4; q++) {
            float2 f0 = __half22float2(*(__half2*)(((unsigned*)&v0) + q));
            float2 f1 = __half22float2(*(__half2*)(((unsigned*)&v1) + q));
            float2 f2 = __half22float2(*(__half2*)(((unsigned*)&v2) + q));
            float2 f3 = __half22float2(*(__half2*)(((unsigned*)&v3) + q));
            acc[2 * q]     = fmaf(f0.x, c0, acc[2 * q]);
            acc[2 * q + 1] = fmaf(f0.y, c0, acc[2 * q + 1]);
            acc[2 * q]     = fmaf(f1.x, c1, acc[2 * q]);
            acc[2 * q + 1] = fmaf(f1.y, c1, acc[2 * q + 1]);
            acc[2 * q]     = fmaf(f2.x, c2, acc[2 * q]);
            acc[2 * q + 1] = fmaf(f2.y, c2, acc[2 * q + 1]);
            acc[2 * q]     = fmaf(f3.x, c3, acc[2 * q]);
            acc[2 * q + 1] = fmaf(f3.y, c3, acc[2 * q + 1]);
        }
    }
    for (; e < e1; e++) {
        int s0 = esrc[e];
        float c0 = dinv[s0] * di;
        uint4 v0 = *(const uint4*)(hwh + (size_t)s0 * Hd + l * 8);
#pragma unroll
        for (int q = 0; q < 4; q++) {
            float2 f0 = __half22float2(*(__half2*)(((unsigned*)&v0) + q));
            acc[2 * q]     = fmaf(f0.x, c0, acc[2 * q]);
            acc[2 * q + 1] = fmaf(f0.y, c0, acc[2 * q + 1]);
        }
    }

    *(float4*)(agg + (size_t)node * Hd + l * 8)     = make_float4(acc[0], acc[1], acc[2], acc[3]);
    *(float4*)(agg + (size_t)node * Hd + l * 8 + 4) = make_float4(acc[4], acc[5], acc[6], acc[7]);

    // bn stats: block reduce over 32 node slots, sharded atomics
    __shared__ float ls[2048];
    *(float4*)&ls[g * 64 + l * 8]     = make_float4(acc[0], acc[1], acc[2], acc[3]);
    *(float4*)&ls[g * 64 + l * 8 + 4] = make_float4(acc[4], acc[5], acc[6], acc[7]);
    __syncthreads();
    int t = threadIdx.x;
    if (t < 64) {
        float s = 0.f, s2 = 0.f;
#pragma unroll
        for (int gg = 0; gg < 32; gg++) {
            float vv = ls[gg * 64 + t];
            s += vv;
            s2 = fmaf(vv, vv, s2);
        }
        float* a = bnacc + (blockIdx.x & 63) * 128;
        atomicAdd(&a[t], s);
        atomicAdd(&a[64 + t], s2);
    }
}

__global__ void k_bnfinal(const float* __restrict__ acc, const float* __restrict__ gamma,
                          const float* __restrict__ beta, float* __restrict__ bnsc,
                          float* __restrict__ bnsh) {
    int c = threadIdx.x;
    if (c >= 64) return;
    float s = 0.f, s2 = 0.f;
    for (int sh = 0; sh < 64; sh++) {
        s  += acc[sh * 128 + c];
        s2 += acc[sh * 128 + 64 + c];
    }
    float mean = s / (float)Nn;
    float var = s2 / (float)Nn - mean * mean;
    var = fmaxf(var, 0.f);
    float sc = gamma[c] * rsqrtf(var + BN_EPS);
    bnsc[c] = sc;
    bnsh[c] = beta[c] - mean * sc;
}

__global__ __launch_bounds__(1024) void k_poolF(const float* __restrict__ agg,
                                                const float* __restrict__ bnsc,
                                                const float* __restrict__ bnsh,
                                                const float* __restrict__ h,
                                                const int* __restrict__ gstart,
                                                float* __restrict__ pooled) {
    int g = blockIdx.x;
    int t = threadIdx.x;
    int ch = t & 63, sl = t >> 6;
    float sc = bnsc[ch], shv = bnsh[ch];
    int n0 = gstart[g], n1 = gstart[g + 1];
    float s = 0.f;
    for (int n = n0 + sl; n < n1; n += 16) {
        float a  = agg[(size_t)n * Hd + ch];
        float ho = h[(size_t)n * Hd + ch];
        s += fmaxf(fmaf(a, sc, shv), 0.f) + ho;
    }
    __shared__ float ls[1024];
    ls[t] = s;
    __syncthreads();
    if (t < 64) {
        float acc = 0.f;
#pragma unroll
        for (int k = 0; k < 16; k++) acc += ls[k * 64 + t];
        float cnt = (float)(n1 - n0);
        pooled[g * Hd + t] = acc / fmaxf(cnt, 1.0f);
    }
}

__global__ __launch_bounds__(256) void k_head(const float* __restrict__ pooled,
                                              const float* __restrict__ w1,
                                              const float* __restrict__ b1,
                                              const float* __restrict__ w2,
                                              const float* __restrict__ b2,
                                              float* __restrict__ out) {
    __shared__ float sw1[Hd * 32], sw2[32], sb1[32];
    int t = threadIdx.x;
    for (int i = t; i < Hd * 32; i += 256) sw1[i] = w1[i];
    if (t < 32) { sw2[t] = w2[t]; sb1[t] = b1[t]; }
    __syncthreads();
    float acc2[32];
#pragma unroll
    for (int k = 0; k < 32; k++) acc2[k] = sb1[k];
    for (int j = 0; j < Hd; j++) {
        float pj = pooled[t * Hd + j];
#pragma unroll
        for (int k = 0; k < 32; k++) acc2[k] = fmaf(pj, sw1[j * 32 + k], acc2[k]);
    }
    float o = b2[0];
#pragma unroll
    for (int k = 0; k < 32; k++) o += fmaxf(acc2[k], 0.f) * sw2[k];
    out[t] = o;
}

// ---------------- launch ----------------

extern "C" void kernel_launch(void* const* d_in, const int* in_sizes, int n_in,
                              void* d_out, int out_size, void* d_ws, size_t ws_size,
                              hipStream_t stream) {
    const float* x       = (const float*)d_in[0];
    const int*   eidx    = (const int*)d_in[1];
    const int*   batch   = (const int*)d_in[2];
    const float* w_embed = (const float*)d_in[3];
    const float* b_embed = (const float*)d_in[4];
    const float* conv_W  = (const float*)d_in[5];
    const float* conv_b  = (const float*)d_in[6];
    const float* gamma   = (const float*)d_in[7];
    const float* beta    = (const float*)d_in[8];
    const float* w1      = (const float*)d_in[9];
    const float* b1      = (const float*)d_in[10];
    const float* w2      = (const float*)d_in[11];
    const float* b2      = (const float*)d_in[12];
    const int* src = eidx;
    const int* dst = eidx + Ne;

    char* p = (char*)d_ws;
    auto alloc = [&](size_t bytes) -> void* {
        void* r = (void*)p;
        p += (bytes + 255) / 256 * 256;
        return r;
    };
    float*    h       = (float*)alloc((size_t)Nn * Hd * 4);
    unsigned short* hwh = (unsigned short*)alloc((size_t)Nn * Hd * 2);
    float*    agg     = (float*)alloc((size_t)Nn * Hd * 4);
    int*      deg     = (int*)alloc((size_t)Nn * 4);
    int*      row_off = (int*)alloc((size_t)(Nn + 1) * 4);
    float*    dinv    = (float*)alloc((size_t)Nn * 4);
    int*      bsum    = (int*)alloc(512 * 4);
    int*      esrc    = (int*)alloc((size_t)Ne * 4);
    unsigned* tpack   = (unsigned*)alloc((size_t)NBLK * CHUNK * 4);
    unsigned short* idx16 = (unsigned short*)alloc((size_t)NBLK * IDXW * 2);
    float*    bnacc   = (float*)alloc((size_t)Ll * 64 * 128 * 4);
    float*    bnsc    = (float*)alloc(64 * 4);
    float*    bnsh    = (float*)alloc(64 * 4);
    float*    pooled  = (float*)alloc((size_t)Gg * Hd * 4);
    int*      gstart  = (int*)alloc((size_t)(Gg + 1) * 4);
    (void)ws_size; (void)in_sizes; (void)n_in; (void)out_size;

    const int NB_N = (Nn + 255) / 256;       // 391
    const int NB_G32 = (Nn + 31) / 32;       // 3125

    hipMemsetAsync(bnacc, 0, (size_t)Ll * 64 * 128 * 4, stream);

    k_part<<<NBLK, 256, 0, stream>>>(src, dst, tpack, idx16);
    k_deg2<<<NBINS, 256, 0, stream>>>(tpack, idx16, deg);
    k_scanA<<<NB_N, 256, 0, stream>>>(deg, row_off, bsum);
    k_scanB<<<1, 512, 0, stream>>>(bsum, NB_N);
    k_scanC<<<NB_N, 256, 0, stream>>>(row_off, bsum);
    k_dinv<<<NB_N, 256, 0, stream>>>(deg, dinv);
    k_csr<<<NBINS, 256, 0, stream>>>(row_off, tpack, idx16, esrc);
    k_gstart<<<1, 256, 0, stream>>>(batch, gstart);

    k_embed_gemm2<<<NGB, 256, 0, stream>>>(x, w_embed, b_embed, conv_W, h, hwh);

    for (int i = 0; i < Ll; i++) {
        if (i > 0)
            k_gemmF2<<<NGB, 256, 0, stream>>>(agg, bnsc, bnsh, h,
                                              conv_W + (size_t)i * Hd * Hd, hwh);
        k_gatherH<<<NB_G32, 256, 0, stream>>>(hwh, dinv, row_off, esrc,
                                              conv_b + (size_t)i * Hd, agg,
                                              bnacc + (size_t)i * 64 * 128);
        k_bnfinal<<<1, 64, 0, stream>>>(bnacc + (size_t)i * 64 * 128,
                                        gamma + (size_t)i * Hd,
                                        beta + (size_t)i * Hd, bnsc, bnsh);
    }

    k_poolF<<<Gg, 1024, 0, stream>>>(agg, bnsc, bnsh, h, gstart, pooled);
    k_head<<<1, 256, 0, stream>>>(pooled, w1, b1, w2, b2, (float*)d_out);
}

// Round 9
// 340.273 us; speedup vs baseline: 3.2900x; 1.3184x over previous
//
#include <hip/hip_runtime.h>
#include <hip/hip_fp16.h>

#define Nn 100000
#define Ne 1600000
#define Fi 32
#define Hd 64
#define Ll 4
#define Gg 256
#define BN_EPS 1e-5f
#define NPB 128                      // nodes per bucket
#define NBINS ((Nn + NPB - 1) / NPB) // 782 buckets
#define CHUNK 8192                   // edges per partition block
#define NBLK ((Ne + CHUNK - 1) / CHUNK) // 196 partition blocks
#define IDXW (NBINS + 2)             // 784, u16 row stride
#define TPAD 68                      // padded LDS row stride for 64-wide tiles
#define XPAD 36                      // padded LDS row stride for 32-wide tiles
#define NGB ((Nn + 63) / 64)         // 1563 GEMM tiles

// ---------------- setup kernels ----------------

__global__ void k_dinv(const int* __restrict__ deg, float* __restrict__ dinv) {
    int n = blockIdx.x * blockDim.x + threadIdx.x;
    if (n < Nn) dinv[n] = rsqrtf((float)deg[n] + 1.0f);
}

__global__ void k_scanA(const int* __restrict__ deg, int* __restrict__ row_off,
                        int* __restrict__ bsum) {
    __shared__ int s[256];
    int t = threadIdx.x;
    int i = blockIdx.x * 256 + t;
    int v = (i < Nn) ? deg[i] : 0;
    s[t] = v;
    __syncthreads();
    int x = v;
    for (int off = 1; off < 256; off <<= 1) {
        int u = (t >= off) ? s[t - off] : 0;
        __syncthreads();
        x += u;
        s[t] = x;
        __syncthreads();
    }
    if (i < Nn) row_off[i] = x - v;
    if (t == 255) bsum[blockIdx.x] = x;
}

__global__ void k_scanB(int* __restrict__ bsum, int nblk) {
    __shared__ int s[512];
    int t = threadIdx.x;
    int v = (t < nblk) ? bsum[t] : 0;
    s[t] = v;
    __syncthreads();
    int x = v;
    for (int off = 1; off < 512; off <<= 1) {
        int u = (t >= off) ? s[t - off] : 0;
        __syncthreads();
        x += u;
        s[t] = x;
        __syncthreads();
    }
    if (t < nblk) bsum[t] = x - v;
}

__global__ void k_scanC(int* __restrict__ row_off, const int* __restrict__ bsum) {
    int i = blockIdx.x * 256 + threadIdx.x;
    if (i < Nn) row_off[i] += bsum[blockIdx.x];
    if (i == 0) row_off[Nn] = Ne;
}

// block-major partition (no global atomics, coalesced writes)
__global__ __launch_bounds__(256) void k_part(const int* __restrict__ src,
                                              const int* __restrict__ dst,
                                              unsigned* __restrict__ tpack,
                                              unsigned short* __restrict__ idx16) {
    __shared__ int hist[NBINS];
    __shared__ int lofs[NBINS + 1];
    __shared__ int wsum[256];
    __shared__ unsigned stage[CHUNK];
    int blk = blockIdx.x, t = threadIdx.x;
    int e0 = blk * CHUNK;
    int nval = min(CHUNK, Ne - e0);

    for (int i = t; i < NBINS; i += 256) hist[i] = 0;
    __syncthreads();
    for (int i = t; i < nval; i += 256)
        atomicAdd(&hist[dst[e0 + i] >> 7], 1);
    __syncthreads();

    int base = t * 4;
    int loc[4];
    int s = 0;
#pragma unroll
    for (int k = 0; k < 4; k++) {
        int b = base + k;
        int c = (b < NBINS) ? hist[b] : 0;
        loc[k] = s;
        s += c;
    }
    wsum[t] = s;
    __syncthreads();
    int x = s;
    for (int off = 1; off < 256; off <<= 1) {
        int u = (t >= off) ? wsum[t - off] : 0;
        __syncthreads();
        x += u;
        wsum[t] = x;
        __syncthreads();
    }
    int excl = x - s;
#pragma unroll
    for (int k = 0; k < 4; k++) {
        int b = base + k;
        if (b < NBINS) lofs[b] = excl + loc[k];
    }
    if (t == 0) lofs[NBINS] = nval;
    __syncthreads();

    for (int i = t; i <= NBINS; i += 256)
        idx16[(size_t)blk * IDXW + i] = (unsigned short)lofs[i];

    for (int i = t; i < NBINS; i += 256) hist[i] = lofs[i];
    __syncthreads();
    for (int i = t; i < nval; i += 256) {
        int d = dst[e0 + i];
        int sv = src[e0 + i];
        int p = atomicAdd(&hist[d >> 7], 1);
        stage[p] = (unsigned)sv | ((unsigned)(d & (NPB - 1)) << 17);
    }
    __syncthreads();
    for (int i = t; i < nval; i += 256)
        tpack[(size_t)blk * CHUNK + i] = stage[i];
}

// degree from partitioned tpack
__global__ __launch_bounds__(256) void k_deg2(const unsigned* __restrict__ tpack,
                                              const unsigned short* __restrict__ idx16,
                                              int* __restrict__ deg) {
    __shared__ int cnt[NPB];
    int b = blockIdx.x, t = threadIdx.x;
    if (t < NPB) cnt[t] = 0;
    __syncthreads();
    if (t < NBLK) {
        const unsigned short* row = idx16 + (size_t)t * IDXW;
        int s = row[b], e = row[b + 1];
        const unsigned* tp = tpack + (size_t)t * CHUNK;
        for (int k = s; k < e; k++)
            atomicAdd(&cnt[tp[k] >> 17], 1);
    }
    __syncthreads();
    int node = b * NPB + t;
    if (t < NPB && node < Nn) deg[node] = cnt[t];
}

// per-bucket CSR scatter
__global__ __launch_bounds__(256) void k_csr(const int* __restrict__ row_off,
                                             const unsigned* __restrict__ tpack,
                                             const unsigned short* __restrict__ idx16,
                                             int* __restrict__ esrc) {
    __shared__ int cur[NPB];
    int b = blockIdx.x, t = threadIdx.x;
    int n0 = b * NPB;
    int e0 = row_off[n0];
    if (t < NPB) {
        int node = n0 + t;
        cur[t] = (node < Nn) ? (row_off[node] - e0) : 0;
    }
    __syncthreads();
    if (t < NBLK) {
        const unsigned short* row = idx16 + (size_t)t * IDXW;
        int s = row[b], e = row[b + 1];
        const unsigned* tp = tpack + (size_t)t * CHUNK;
        for (int k = s; k < e; k++) {
            unsigned v = tp[k];
            int p = atomicAdd(&cur[v >> 17], 1);
            esrc[e0 + p] = (int)(v & 0x1FFFFu);
        }
    }
}

__global__ void k_gstart(const int* __restrict__ batch, int* __restrict__ gstart) {
    int g = threadIdx.x;
    int lo = 0, hi = Nn;
    while (lo < hi) {
        int mid = (lo + hi) >> 1;
        if (batch[mid] < g) lo = mid + 1; else hi = mid;
    }
    gstart[g] = lo;
    if (g == 0) gstart[Gg] = Nn;
}

// ---------------- tiled GEMM kernels ----------------

#define MT_FMA(AV, W0, W1, W2, W3, R)                                          \
    acc[R][0] = fmaf(AV.x, W0.x, acc[R][0]);                                   \
    acc[R][0] = fmaf(AV.y, W1.x, acc[R][0]);                                   \
    acc[R][0] = fmaf(AV.z, W2.x, acc[R][0]);                                   \
    acc[R][0] = fmaf(AV.w, W3.x, acc[R][0]);                                   \
    acc[R][1] = fmaf(AV.x, W0.y, acc[R][1]);                                   \
    acc[R][1] = fmaf(AV.y, W1.y, acc[R][1]);                                   \
    acc[R][1] = fmaf(AV.z, W2.y, acc[R][1]);                                   \
    acc[R][1] = fmaf(AV.w, W3.y, acc[R][1]);                                   \
    acc[R][2] = fmaf(AV.x, W0.z, acc[R][2]);                                   \
    acc[R][2] = fmaf(AV.y, W1.z, acc[R][2]);                                   \
    acc[R][2] = fmaf(AV.z, W2.z, acc[R][2]);                                   \
    acc[R][2] = fmaf(AV.w, W3.z, acc[R][2]);                                   \
    acc[R][3] = fmaf(AV.x, W0.w, acc[R][3]);                                   \
    acc[R][3] = fmaf(AV.y, W1.w, acc[R][3]);                                   \
    acc[R][3] = fmaf(AV.z, W2.w, acc[R][3]);                                   \
    acc[R][3] = fmaf(AV.w, W3.w, acc[R][3]);

__device__ inline void store_half4(unsigned short* dst, float a, float b,
                                   float c, float d) {
    __half2 p0 = __floats2half2_rn(a, b);
    __half2 p1 = __floats2half2_rn(c, d);
    uint2 u;
    u.x = *(unsigned*)&p0;
    u.y = *(unsigned*)&p1;
    *(uint2*)dst = u;
}

// fused: hn = relu(agg*sc+sh)+h (write h), hw = hn@W (write hwh as fp16)
// __launch_bounds__(256,4): VGPR<=128 -> 4 waves/SIMD; LDS 34KB -> 4 blocks/CU
__global__ __launch_bounds__(256, 4) void k_gemmF2(const float* __restrict__ agg,
                                                   const float* __restrict__ bnsc,
                                                   const float* __restrict__ bnsh,
                                                   float* __restrict__ h,
                                                   const float* __restrict__ W,
                                                   unsigned short* __restrict__ hwh) {
    __shared__ float hs[64 * TPAD];
    __shared__ float ws[64 * 64];
    int t = threadIdx.x;
    int n0 = blockIdx.x * 64;

    for (int f = t; f < 1024; f += 256)
        ((float4*)ws)[f] = ((const float4*)W)[f];

    for (int f = t; f < 1024; f += 256) {
        int row = f >> 4, c4 = (f & 15) * 4;
        int node = n0 + row;
        if (node < Nn) {
            float4 a  = *(const float4*)(agg + (size_t)node * Hd + c4);
            float4 ho = *(const float4*)(h + (size_t)node * Hd + c4);
            float4 sc = ((const float4*)bnsc)[f & 15];
            float4 sh = ((const float4*)bnsh)[f & 15];
            float4 r4;
            r4.x = fmaxf(fmaf(a.x, sc.x, sh.x), 0.f) + ho.x;
            r4.y = fmaxf(fmaf(a.y, sc.y, sh.y), 0.f) + ho.y;
            r4.z = fmaxf(fmaf(a.z, sc.z, sh.z), 0.f) + ho.z;
            r4.w = fmaxf(fmaf(a.w, sc.w, sh.w), 0.f) + ho.w;
            *(float4*)(h + (size_t)node * Hd + c4) = r4;
            *(float4*)&hs[row * TPAD + c4] = r4;
        } else {
            *(float4*)&hs[row * TPAD + c4] = make_float4(0.f, 0.f, 0.f, 0.f);
        }
    }
    __syncthreads();

    int i = t >> 4, j = t & 15;
    float acc[4][4] = {};
#pragma unroll 2
    for (int k = 0; k < 64; k += 4) {
        float4 w0 = *(const float4*)&ws[(k + 0) * 64 + 4 * j];
        float4 w1 = *(const float4*)&ws[(k + 1) * 64 + 4 * j];
        float4 w2 = *(const float4*)&ws[(k + 2) * 64 + 4 * j];
        float4 w3 = *(const float4*)&ws[(k + 3) * 64 + 4 * j];
        float4 a0 = *(const float4*)&hs[(4 * i + 0) * TPAD + k];
        float4 a1 = *(const float4*)&hs[(4 * i + 1) * TPAD + k];
        float4 a2 = *(const float4*)&hs[(4 * i + 2) * TPAD + k];
        float4 a3 = *(const float4*)&hs[(4 * i + 3) * TPAD + k];
        MT_FMA(a0, w0, w1, w2, w3, 0)
        MT_FMA(a1, w0, w1, w2, w3, 1)
        MT_FMA(a2, w0, w1, w2, w3, 2)
        MT_FMA(a3, w0, w1, w2, w3, 3)
    }
#pragma unroll
    for (int r = 0; r < 4; r++) {
        int node = n0 + 4 * i + r;
        if (node < Nn)
            store_half4(hwh + (size_t)node * Hd + 4 * j,
                        acc[r][0], acc[r][1], acc[r][2], acc[r][3]);
    }
}

// fused: h = x@we+be (write h), hw = h@W0 (write hwh as fp16)
// LDS union: ws aliases xs+wes (phase-2 only); total ~35KB
__global__ __launch_bounds__(256, 4) void k_embed_gemm2(const float* __restrict__ x,
                                                        const float* __restrict__ we,
                                                        const float* __restrict__ be,
                                                        const float* __restrict__ W,
                                                        float* __restrict__ h,
                                                        unsigned short* __restrict__ hwh) {
    __shared__ float uni[64 * XPAD + 32 * 64];   // phase1: xs+wes / phase2: ws
    __shared__ float hs[64 * TPAD];
    __shared__ float bes[64];
    float* xs  = uni;                 // 64*36 = 2304 floats
    float* wes = uni + 64 * XPAD;     // 2048 floats
    float* ws  = uni;                 // 4096 floats (phase 2)
    int t = threadIdx.x;
    int n0 = blockIdx.x * 64;

    for (int f = t; f < 512; f += 256)
        ((float4*)wes)[f] = ((const float4*)we)[f];
    if (t < 64) bes[t] = be[t];

    for (int f = t; f < 512; f += 256) {
        int row = f >> 3, c4 = (f & 7) * 4;
        int node = n0 + row;
        float4 v = (node < Nn) ? *(const float4*)(x + (size_t)node * Fi + c4)
                               : make_float4(0.f, 0.f, 0.f, 0.f);
        *(float4*)&xs[row * XPAD + c4] = v;
    }
    __syncthreads();

    int i = t >> 4, j = t & 15;
    {
        float acc[4][4];
#pragma unroll
        for (int r = 0; r < 4; r++)
#pragma unroll
            for (int c = 0; c < 4; c++) acc[r][c] = bes[4 * j + c];
#pragma unroll 2
        for (int k = 0; k < 32; k += 4) {
            float4 w0 = *(const float4*)&wes[(k + 0) * 64 + 4 * j];
            float4 w1 = *(const float4*)&wes[(k + 1) * 64 + 4 * j];
            float4 w2 = *(const float4*)&wes[(k + 2) * 64 + 4 * j];
            float4 w3 = *(const float4*)&wes[(k + 3) * 64 + 4 * j];
            float4 a0 = *(const float4*)&xs[(4 * i + 0) * XPAD + k];
            float4 a1 = *(const float4*)&xs[(4 * i + 1) * XPAD + k];
            float4 a2 = *(const float4*)&xs[(4 * i + 2) * XPAD + k];
            float4 a3 = *(const float4*)&xs[(4 * i + 3) * XPAD + k];
            MT_FMA(a0, w0, w1, w2, w3, 0)
            MT_FMA(a1, w0, w1, w2, w3, 1)
            MT_FMA(a2, w0, w1, w2, w3, 2)
            MT_FMA(a3, w0, w1, w2, w3, 3)
        }
#pragma unroll
        for (int r = 0; r < 4; r++) {
            int node = n0 + 4 * i + r;
            float4 hv = make_float4(acc[r][0], acc[r][1], acc[r][2], acc[r][3]);
            *(float4*)&hs[(4 * i + r) * TPAD + 4 * j] = hv;
            if (node < Nn)
                *(float4*)(h + (size_t)node * Hd + 4 * j) = hv;
        }
    }
    __syncthreads();                      // phase-1 reads of xs/wes done
    for (int f = t; f < 1024; f += 256)
        ((float4*)ws)[f] = ((const float4*)W)[f];
    __syncthreads();
    {
        float acc[4][4] = {};
#pragma unroll 2
        for (int k = 0; k < 64; k += 4) {
            float4 w0 = *(const float4*)&ws[(k + 0) * 64 + 4 * j];
            float4 w1 = *(const float4*)&ws[(k + 1) * 64 + 4 * j];
            float4 w2 = *(const float4*)&ws[(k + 2) * 64 + 4 * j];
            float4 w3 = *(const float4*)&ws[(k + 3) * 64 + 4 * j];
            float4 a0 = *(const float4*)&hs[(4 * i + 0) * TPAD + k];
            float4 a1 = *(const float4*)&hs[(4 * i + 1) * TPAD + k];
            float4 a2 = *(const float4*)&hs[(4 * i + 2) * TPAD + k];
            float4 a3 = *(const float4*)&hs[(4 * i + 3) * TPAD + k];
            MT_FMA(a0, w0, w1, w2, w3, 0)
            MT_FMA(a1, w0, w1, w2, w3, 1)
            MT_FMA(a2, w0, w1, w2, w3, 2)
            MT_FMA(a3, w0, w1, w2, w3, 3)
        }
#pragma unroll
        for (int r = 0; r < 4; r++) {
            int node = n0 + 4 * i + r;
            if (node < Nn)
                store_half4(hwh + (size_t)node * Hd + 4 * j,
                            acc[r][0], acc[r][1], acc[r][2], acc[r][3]);
        }
    }
}

// ---------------- gather / bn / pool / head ----------------

// fp16 gather: 8 lanes per node, 8 channels per lane (uint4 = 8 halves)
__global__ __launch_bounds__(256) void k_gatherH(const unsigned short* __restrict__ hwh,
                                                 const float* __restrict__ dinv,
                                                 const int* __restrict__ row_off,
                                                 const int* __restrict__ esrc,
                                                 const float* __restrict__ bias,
                                                 float* __restrict__ agg,
                                                 float* __restrict__ bnacc) {
    int g = threadIdx.x >> 3;   // 32 node slots
    int l = threadIdx.x & 7;    // lane in node group
    int node = blockIdx.x * 32 + g;   // Nn % 32 == 0
    float di = dinv[node];
    float scl = di * di;
    float acc[8];

    uint4 v = *(const uint4*)(hwh + (size_t)node * Hd + l * 8);
#pragma unroll
    for (int q = 0; q < 4; q++) {
        __half2 hp = *(__half2*)(((unsigned*)&v) + q);
        float2 f = __half22float2(hp);
        acc[2 * q]     = f.x * scl + bias[l * 8 + 2 * q];
        acc[2 * q + 1] = f.y * scl + bias[l * 8 + 2 * q + 1];
    }

    int e = row_off[node], e1 = row_off[node + 1];
    for (; e + 3 < e1; e += 4) {
        int s0 = esrc[e], s1 = esrc[e + 1], s2 = esrc[e + 2], s3 = esrc[e + 3];
        float c0 = dinv[s0] * di, c1 = dinv[s1] * di;
        float c2 = dinv[s2] * di, c3 = dinv[s3] * di;
        uint4 v0 = *(const uint4*)(hwh + (size_t)s0 * Hd + l * 8);
        uint4 v1 = *(const uint4*)(hwh + (size_t)s1 * Hd + l * 8);
        uint4 v2 = *(const uint4*)(hwh + (size_t)s2 * Hd + l * 8);
        uint4 v3 = *(const uint4*)(hwh + (size_t)s3 * Hd + l * 8);
#pragma unroll
        for (int q = 0; q < 4; q++) {
            float2 f0 = __half22float2(*(__half2*)(((unsigned*)&v0) + q));
            float2 f1 = __half22float2(*(__half2*)(((unsigned*)&v1) + q));
            float2 f2 = __half22float2(*(__half2*)(((unsigned*)&v2) + q));
            float2 f3 = __half22float2(*(__half2*)(((unsigned*)&v3) + q));
            acc[2 * q]     = fmaf(f0.x, c0, acc[2 * q]);
            acc[2 * q + 1] = fmaf(f0.y, c0, acc[2 * q + 1]);
            acc[2 * q]     = fmaf(f1.x, c1, acc[2 * q]);
            acc[2 * q + 1] = fmaf(f1.y, c1, acc[2 * q + 1]);
            acc[2 * q]     = fmaf(f2.x, c2, acc[2 * q]);
            acc[2 * q + 1] = fmaf(f2.y, c2, acc[2 * q + 1]);
            acc[2 * q]     = fmaf(f3.x, c3, acc[2 * q]);
            acc[2 * q + 1] = fmaf(f3.y, c3, acc[2 * q + 1]);
        }
    }
    for (; e < e1; e++) {
        int s0 = esrc[e];
        float c0 = dinv[s0] * di;
        uint4 v0 = *(const uint4*)(hwh + (size_t)s0 * Hd + l * 8);
#pragma unroll
        for (int q = 0; q < 4; q++) {
            float2 f0 = __half22float2(*(__half2*)(((unsigned*)&v0) + q));
            acc[2 * q]     = fmaf(f0.x, c0, acc[2 * q]);
            acc[2 * q + 1] = fmaf(f0.y, c0, acc[2 * q + 1]);
        }
    }

    *(float4*)(agg + (size_t)node * Hd + l * 8)     = make_float4(acc[0], acc[1], acc[2], acc[3]);
    *(float4*)(agg + (size_t)node * Hd + l * 8 + 4) = make_float4(acc[4], acc[5], acc[6], acc[7]);

    __shared__ float ls[2048];
    *(float4*)&ls[g * 64 + l * 8]     = make_float4(acc[0], acc[1], acc[2], acc[3]);
    *(float4*)&ls[g * 64 + l * 8 + 4] = make_float4(acc[4], acc[5], acc[6], acc[7]);
    __syncthreads();
    int t = threadIdx.x;
    if (t < 64) {
        float s = 0.f, s2 = 0.f;
#pragma unroll
        for (int gg = 0; gg < 32; gg++) {
            float vv = ls[gg * 64 + t];
            s += vv;
            s2 = fmaf(vv, vv, s2);
        }
        float* a = bnacc + (blockIdx.x & 63) * 128;
        atomicAdd(&a[t], s);
        atomicAdd(&a[64 + t], s2);
    }
}

__global__ void k_bnfinal(const float* __restrict__ acc, const float* __restrict__ gamma,
                          const float* __restrict__ beta, float* __restrict__ bnsc,
                          float* __restrict__ bnsh) {
    int c = threadIdx.x;
    if (c >= 64) return;
    float s = 0.f, s2 = 0.f;
    for (int sh = 0; sh < 64; sh++) {
        s  += acc[sh * 128 + c];
        s2 += acc[sh * 128 + 64 + c];
    }
    float mean = s / (float)Nn;
    float var = s2 / (float)Nn - mean * mean;
    var = fmaxf(var, 0.f);
    float sc = gamma[c] * rsqrtf(var + BN_EPS);
    bnsc[c] = sc;
    bnsh[c] = beta[c] - mean * sc;
}

__global__ __launch_bounds__(1024) void k_poolF(const float* __restrict__ agg,
                                                const float* __restrict__ bnsc,
                                                const float* __restrict__ bnsh,
                                                const float* __restrict__ h,
                                                const int* __restrict__ gstart,
                                                float* __restrict__ pooled) {
    int g = blockIdx.x;
    int t = threadIdx.x;
    int ch = t & 63, sl = t >> 6;
    float sc = bnsc[ch], shv = bnsh[ch];
    int n0 = gstart[g], n1 = gstart[g + 1];
    float s = 0.f;
    for (int n = n0 + sl; n < n1; n += 16) {
        float a  = agg[(size_t)n * Hd + ch];
        float ho = h[(size_t)n * Hd + ch];
        s += fmaxf(fmaf(a, sc, shv), 0.f) + ho;
    }
    __shared__ float ls[1024];
    ls[t] = s;
    __syncthreads();
    if (t < 64) {
        float acc = 0.f;
#pragma unroll
        for (int k = 0; k < 16; k++) acc += ls[k * 64 + t];
        float cnt = (float)(n1 - n0);
        pooled[g * Hd + t] = acc / fmaxf(cnt, 1.0f);
    }
}

__global__ __launch_bounds__(256) void k_head(const float* __restrict__ pooled,
                                              const float* __restrict__ w1,
                                              const float* __restrict__ b1,
                                              const float* __restrict__ w2,
                                              const float* __restrict__ b2,
                                              float* __restrict__ out) {
    __shared__ float sw1[Hd * 32], sw2[32], sb1[32];
    int t = threadIdx.x;
    for (int i = t; i < Hd * 32; i += 256) sw1[i] = w1[i];
    if (t < 32) { sw2[t] = w2[t]; sb1[t] = b1[t]; }
    __syncthreads();
    float acc2[32];
#pragma unroll
    for (int k = 0; k < 32; k++) acc2[k] = sb1[k];
    for (int j = 0; j < Hd; j++) {
        float pj = pooled[t * Hd + j];
#pragma unroll
        for (int k = 0; k < 32; k++) acc2[k] = fmaf(pj, sw1[j * 32 + k], acc2[k]);
    }
    float o = b2[0];
#pragma unroll
    for (int k = 0; k < 32; k++) o += fmaxf(acc2[k], 0.f) * sw2[k];
    out[t] = o;
}

// ---------------- launch ----------------

extern "C" void kernel_launch(void* const* d_in, const int* in_sizes, int n_in,
                              void* d_out, int out_size, void* d_ws, size_t ws_size,
                              hipStream_t stream) {
    const float* x       = (const float*)d_in[0];
    const int*   eidx    = (const int*)d_in[1];
    const int*   batch   = (const int*)d_in[2];
    const float* w_embed = (const float*)d_in[3];
    const float* b_embed = (const float*)d_in[4];
    const float* conv_W  = (const float*)d_in[5];
    const float* conv_b  = (const float*)d_in[6];
    const float* gamma   = (const float*)d_in[7];
    const float* beta    = (const float*)d_in[8];
    const float* w1      = (const float*)d_in[9];
    const float* b1      = (const float*)d_in[10];
    const float* w2      = (const float*)d_in[11];
    const float* b2      = (const float*)d_in[12];
    const int* src = eidx;
    const int* dst = eidx + Ne;

    char* p = (char*)d_ws;
    auto alloc = [&](size_t bytes) -> void* {
        void* r = (void*)p;
        p += (bytes + 255) / 256 * 256;
        return r;
    };
    float*    h       = (float*)alloc((size_t)Nn * Hd * 4);
    unsigned short* hwh = (unsigned short*)alloc((size_t)Nn * Hd * 2);
    float*    agg     = (float*)alloc((size_t)Nn * Hd * 4);
    int*      deg     = (int*)alloc((size_t)Nn * 4);
    int*      row_off = (int*)alloc((size_t)(Nn + 1) * 4);
    float*    dinv    = (float*)alloc((size_t)Nn * 4);
    int*      bsum    = (int*)alloc(512 * 4);
    int*      esrc    = (int*)alloc((size_t)Ne * 4);
    unsigned* tpack   = (unsigned*)alloc((size_t)NBLK * CHUNK * 4);
    unsigned short* idx16 = (unsigned short*)alloc((size_t)NBLK * IDXW * 2);
    float*    bnacc   = (float*)alloc((size_t)Ll * 64 * 128 * 4);
    float*    bnsc    = (float*)alloc(64 * 4);
    float*    bnsh    = (float*)alloc(64 * 4);
    float*    pooled  = (float*)alloc((size_t)Gg * Hd * 4);
    int*      gstart  = (int*)alloc((size_t)(Gg + 1) * 4);
    (void)ws_size; (void)in_sizes; (void)n_in; (void)out_size;

    const int NB_N = (Nn + 255) / 256;       // 391
    const int NB_G32 = (Nn + 31) / 32;       // 3125

    hipMemsetAsync(bnacc, 0, (size_t)Ll * 64 * 128 * 4, stream);

    k_part<<<NBLK, 256, 0, stream>>>(src, dst, tpack, idx16);
    k_deg2<<<NBINS, 256, 0, stream>>>(tpack, idx16, deg);
    k_scanA<<<NB_N, 256, 0, stream>>>(deg, row_off, bsum);
    k_scanB<<<1, 512, 0, stream>>>(bsum, NB_N);
    k_scanC<<<NB_N, 256, 0, stream>>>(row_off, bsum);
    k_dinv<<<NB_N, 256, 0, stream>>>(deg, dinv);
    k_csr<<<NBINS, 256, 0, stream>>>(row_off, tpack, idx16, esrc);
    k_gstart<<<1, 256, 0, stream>>>(batch, gstart);

    k_embed_gemm2<<<NGB, 256, 0, stream>>>(x, w_embed, b_embed, conv_W, h, hwh);

    for (int i = 0; i < Ll; i++) {
        if (i > 0)
            k_gemmF2<<<NGB, 256, 0, stream>>>(agg, bnsc, bnsh, h,
                                              conv_W + (size_t)i * Hd * Hd, hwh);
        k_gatherH<<<NB_G32, 256, 0, stream>>>(hwh, dinv, row_off, esrc,
                                              conv_b + (size_t)i * Hd, agg,
                                              bnacc + (size_t)i * 64 * 128);
        k_bnfinal<<<1, 64, 0, stream>>>(bnacc + (size_t)i * 64 * 128,
                                        gamma + (size_t)i * Hd,
                                        beta + (size_t)i * Hd, bnsc, bnsh);
    }

    k_poolF<<<Gg, 1024, 0, stream>>>(agg, bnsc, bnsh, h, gstart, pooled);
    k_head<<<1, 256, 0, stream>>>(pooled, w1, b1, w2, b2, (float*)d_out);
}